// Round 1
// baseline (402.420 us; speedup 1.0000x reference)
//
#include <hip/hip_runtime.h>

#define DEV __device__ __forceinline__

typedef __attribute__((ext_vector_type(8))) short short8;
typedef __attribute__((ext_vector_type(4))) float f32x4;

constexpr int Dm = 768;   // model dim
constexpr int Sn = 2048;  // seq len
constexpr int Bn = 4;     // batch
constexpr int Hn = 12;    // heads
constexpr int Mn = Bn * Sn;  // 8192 rows

DEV unsigned short f32_to_bf16(float f) {
  unsigned int u = __float_as_uint(f);
  u = (u + 0x7fffu + ((u >> 16) & 1u)) >> 16;
  return (unsigned short)u;
}

DEV f32x4 mfma_bf16(short8 a, short8 b, f32x4 c) {
  return __builtin_amdgcn_mfma_f32_16x16x32_bf16(a, b, c, 0, 0, 0);
}

// async global->LDS, 16B per lane; LDS dest = wave-uniform base + lane*16
DEV void gload_lds16(const void* g, void* l) {
  __builtin_amdgcn_global_load_lds(
      (__attribute__((address_space(1))) const unsigned int*)g,
      (__attribute__((address_space(3))) unsigned int*)l, 16, 0, 0);
}

// ---------------- cast kernels ----------------
__global__ __launch_bounds__(256) void k_cast_hidden(const float* __restrict__ src,
                                                     unsigned short* __restrict__ dst) {
  int i = blockIdx.x * 256 + threadIdx.x;  // grid exact: 6144*256*4 = 6291456
  float4 v = ((const float4*)src)[i];
  ushort4 o;
  o.x = f32_to_bf16(v.x); o.y = f32_to_bf16(v.y);
  o.z = f32_to_bf16(v.z); o.w = f32_to_bf16(v.w);
  ((ushort4*)dst)[i] = o;
}

__global__ __launch_bounds__(256) void k_cast_w(const float* __restrict__ Wq,
                                                const float* __restrict__ Wk,
                                                const float* __restrict__ Wv,
                                                const float* __restrict__ Wo,
                                                unsigned short* __restrict__ wbf) {
  const float* src = (blockIdx.y == 0) ? Wq : (blockIdx.y == 1) ? Wk
                   : (blockIdx.y == 2) ? Wv : Wo;
  unsigned short* dst = wbf + (size_t)blockIdx.y * (Dm * Dm);
  int i = blockIdx.x * 256 + threadIdx.x;  // 576*256*4 = 589824
  float4 v = ((const float4*)src)[i];
  ushort4 o;
  o.x = f32_to_bf16(v.x); o.y = f32_to_bf16(v.y);
  o.z = f32_to_bf16(v.z); o.w = f32_to_bf16(v.w);
  ((ushort4*)dst)[i] = o;
}

// ---------------- QKV projection GEMM ----------------
// C[M,N] = A[M,K] * W[N,K]^T + bias ; z=0->Q plain, z=1->K plain, z=2->V transposed [B,H,DH,S]
__global__ __launch_bounds__(256, 3) void k_gemm_qkv(
    const unsigned short* __restrict__ Abf, const unsigned short* __restrict__ wbf,
    const float* __restrict__ bq, const float* __restrict__ bk, const float* __restrict__ bv,
    unsigned short* __restrict__ Qb, unsigned short* __restrict__ Kb,
    unsigned short* __restrict__ Vt) {
  __shared__ unsigned short As[128 * 32];
  __shared__ unsigned short Bs[128 * 32];

  const int tid = threadIdx.x;
  const int wave = tid >> 6, lane = tid & 63;
  const int wm = wave >> 1, wn = wave & 1;
  const int quad = lane >> 4, l16 = lane & 15;
  const int bm = blockIdx.y * 128, bn = blockIdx.x * 128;
  const int z = blockIdx.z;

  const unsigned short* W = wbf + (size_t)z * (Dm * Dm);
  const float* bias = (z == 0) ? bq : ((z == 1) ? bk : bv);

  const int sr = lane >> 2;        // row within 16-row chunk
  const int sc = (lane & 3) * 8;   // col offset (shorts)
  const unsigned short* gA0 = Abf + (size_t)(bm + (wave * 2 + 0) * 16 + sr) * Dm + sc;
  const unsigned short* gA1 = Abf + (size_t)(bm + (wave * 2 + 1) * 16 + sr) * Dm + sc;
  const unsigned short* gB0 = W + (size_t)(bn + (wave * 2 + 0) * 16 + sr) * Dm + sc;
  const unsigned short* gB1 = W + (size_t)(bn + (wave * 2 + 1) * 16 + sr) * Dm + sc;
  unsigned short* lA0 = &As[(wave * 2 + 0) * 512];
  unsigned short* lA1 = &As[(wave * 2 + 1) * 512];
  unsigned short* lB0 = &Bs[(wave * 2 + 0) * 512];
  unsigned short* lB1 = &Bs[(wave * 2 + 1) * 512];

  f32x4 acc[4][4];
#pragma unroll
  for (int i = 0; i < 4; ++i)
#pragma unroll
    for (int j = 0; j < 4; ++j)
#pragma unroll
      for (int r = 0; r < 4; ++r) acc[i][j][r] = 0.f;

  for (int kk = 0; kk < Dm; kk += 32) {
    gload_lds16(gA0 + kk, lA0);
    gload_lds16(gA1 + kk, lA1);
    gload_lds16(gB0 + kk, lB0);
    gload_lds16(gB1 + kk, lB1);
    __syncthreads();
    short8 af[4], bf[4];
#pragma unroll
    for (int mi = 0; mi < 4; ++mi)
      af[mi] = *(const short8*)(&As[(wm * 64 + mi * 16 + l16) * 32 + quad * 8]);
#pragma unroll
    for (int ni = 0; ni < 4; ++ni)
      bf[ni] = *(const short8*)(&Bs[(wn * 64 + ni * 16 + l16) * 32 + quad * 8]);
#pragma unroll
    for (int mi = 0; mi < 4; ++mi)
#pragma unroll
      for (int ni = 0; ni < 4; ++ni)
        acc[mi][ni] = mfma_bf16(af[mi], bf[ni], acc[mi][ni]);
    __syncthreads();
  }

#pragma unroll
  for (int ni = 0; ni < 4; ++ni) {
    int n = bn + wn * 64 + ni * 16 + l16;
    float bias_v = bias[n];
    int h = n >> 6, dcol = n & 63;
#pragma unroll
    for (int mi = 0; mi < 4; ++mi) {
#pragma unroll
      for (int r = 0; r < 4; ++r) {
        int m = bm + wm * 64 + mi * 16 + quad * 4 + r;
        unsigned short o = f32_to_bf16(acc[mi][ni][r] + bias_v);
        if (z == 0)
          Qb[(size_t)m * Dm + n] = o;
        else if (z == 1)
          Kb[(size_t)m * Dm + n] = o;
        else {
          int b = m >> 11, s = m & 2047;
          Vt[((size_t)((b * Hn + h) * 64 + dcol)) * Sn + s] = o;
        }
      }
    }
  }
}

// ---------------- flash attention (mixed softmax + relu^2) ----------------
__global__ __launch_bounds__(256, 2) void k_attn(
    const unsigned short* __restrict__ Qb, const unsigned short* __restrict__ Kb,
    const unsigned short* __restrict__ Vt, const float* __restrict__ wmix,
    unsigned short* __restrict__ Ctx) {
  __shared__ unsigned short Ks[128 * 72];  // K tile [128 kr][64 dh], stride 72 (144B, 2-way ok)
  __shared__ unsigned short Vs[64 * 136];  // V^T tile [64 dh][128 s], stride 136 (272B, 2-way ok)
  __shared__ unsigned short Ps[4 * 32 * 72];  // per-wave P half-tile [32 q][64 k]

  const int tid = threadIdx.x;
  const int wave = tid >> 6, lane = tid & 63;
  const int quad = lane >> 4, l16 = lane & 15;
  const int qt = blockIdx.x;   // 16 q-tiles
  const int bh = blockIdx.y;   // 48 = B*H
  const int b = bh / Hn, h = bh % Hn;

  const unsigned short* Qrow = Qb + (size_t)(b * Sn + qt * 128) * Dm + h * 64;
  const unsigned short* Krow = Kb + (size_t)(b * Sn) * Dm + h * 64;
  const unsigned short* Vrow = Vt + (size_t)bh * 64 * Sn;

  // stage Q tile -> Ks, pull per-wave A-frags into registers
  {
    int r0 = tid >> 3, c = tid & 7;
#pragma unroll
    for (int it = 0; it < 4; ++it) {
      int r = r0 + it * 32;
      uint4 v = *(const uint4*)(Qrow + (size_t)r * Dm + c * 8);
      *(uint4*)(&Ks[r * 72 + c * 8]) = v;
    }
  }
  __syncthreads();
  short8 qf[2][2];
#pragma unroll
  for (int mi = 0; mi < 2; ++mi)
#pragma unroll
    for (int ks = 0; ks < 2; ++ks)
      qf[mi][ks] = *(const short8*)(&Ks[(wave * 32 + mi * 16 + l16) * 72 + ks * 32 + quad * 8]);
  __syncthreads();

  f32x4 acc_s[2][4], acc_r2[2][4];
#pragma unroll
  for (int i = 0; i < 2; ++i)
#pragma unroll
    for (int j = 0; j < 4; ++j)
#pragma unroll
      for (int r = 0; r < 4; ++r) { acc_s[i][j][r] = 0.f; acc_r2[i][j][r] = 0.f; }
  float lp[2][4] = {{0.f, 0.f, 0.f, 0.f}, {0.f, 0.f, 0.f, 0.f}};

  unsigned short* Pw = &Ps[wave * 32 * 72];

  for (int kt = 0; kt < 16; ++kt) {
    // stage K tile and V^T tile
    {
      int r0 = tid >> 3, c = tid & 7;
#pragma unroll
      for (int it = 0; it < 4; ++it) {
        int r = r0 + it * 32;
        uint4 v = *(const uint4*)(Krow + (size_t)(kt * 128 + r) * Dm + c * 8);
        *(uint4*)(&Ks[r * 72 + c * 8]) = v;
      }
      int d0 = tid >> 4, c2 = tid & 15;
#pragma unroll
      for (int it = 0; it < 4; ++it) {
        int d = d0 + it * 16;
        uint4 v = *(const uint4*)(Vrow + (size_t)d * Sn + kt * 128 + c2 * 8);
        *(uint4*)(&Vs[d * 136 + c2 * 8]) = v;
      }
    }
    __syncthreads();

    // QK^T: wave computes 32 q-rows x 128 k-cols
    f32x4 sacc[2][8];
#pragma unroll
    for (int i = 0; i < 2; ++i)
#pragma unroll
      for (int j = 0; j < 8; ++j)
#pragma unroll
        for (int r = 0; r < 4; ++r) sacc[i][j][r] = 0.f;
#pragma unroll
    for (int ks = 0; ks < 2; ++ks) {
      short8 kf[8];
#pragma unroll
      for (int ni = 0; ni < 8; ++ni)
        kf[ni] = *(const short8*)(&Ks[(ni * 16 + l16) * 72 + ks * 32 + quad * 8]);
#pragma unroll
      for (int mi = 0; mi < 2; ++mi)
#pragma unroll
        for (int ni = 0; ni < 8; ++ni)
          sacc[mi][ni] = mfma_bf16(qf[mi][ks], kf[ni], sacc[mi][ni]);
    }

    // pass 1: P = exp(s) (no max-sub needed: |s| bounded ~6), accumulate l and PV_soft
#pragma unroll
    for (int half = 0; half < 2; ++half) {
#pragma unroll
      for (int mi = 0; mi < 2; ++mi)
#pragma unroll
        for (int nj = 0; nj < 4; ++nj) {
          int ni = half * 4 + nj;
#pragma unroll
          for (int r = 0; r < 4; ++r) {
            float s = sacc[mi][ni][r] * 0.125f;
            float p = exp2f(s * 1.4426950408889634f);
            lp[mi][r] += p;
            Pw[(mi * 16 + quad * 4 + r) * 72 + nj * 16 + l16] = f32_to_bf16(p);
          }
        }
#pragma unroll
      for (int ks = 0; ks < 2; ++ks) {
        short8 vf[4], pf[2];
#pragma unroll
        for (int nv = 0; nv < 4; ++nv)
          vf[nv] = *(const short8*)(&Vs[(nv * 16 + l16) * 136 + half * 64 + ks * 32 + quad * 8]);
#pragma unroll
        for (int mi = 0; mi < 2; ++mi)
          pf[mi] = *(const short8*)(&Pw[(mi * 16 + l16) * 72 + ks * 32 + quad * 8]);
#pragma unroll
        for (int mi = 0; mi < 2; ++mi)
#pragma unroll
          for (int nv = 0; nv < 4; ++nv)
            acc_s[mi][nv] = mfma_bf16(pf[mi], vf[nv], acc_s[mi][nv]);
      }
    }

    // pass 2: P = relu(s)^2, accumulate PV_r2
#pragma unroll
    for (int half = 0; half < 2; ++half) {
#pragma unroll
      for (int mi = 0; mi < 2; ++mi)
#pragma unroll
        for (int nj = 0; nj < 4; ++nj) {
          int ni = half * 4 + nj;
#pragma unroll
          for (int r = 0; r < 4; ++r) {
            float s = sacc[mi][ni][r] * 0.125f;
            float t = fmaxf(s, 0.f);
            Pw[(mi * 16 + quad * 4 + r) * 72 + nj * 16 + l16] = f32_to_bf16(t * t);
          }
        }
#pragma unroll
      for (int ks = 0; ks < 2; ++ks) {
        short8 vf[4], pf[2];
#pragma unroll
        for (int nv = 0; nv < 4; ++nv)
          vf[nv] = *(const short8*)(&Vs[(nv * 16 + l16) * 136 + half * 64 + ks * 32 + quad * 8]);
#pragma unroll
        for (int mi = 0; mi < 2; ++mi)
          pf[mi] = *(const short8*)(&Pw[(mi * 16 + l16) * 72 + ks * 32 + quad * 8]);
#pragma unroll
        for (int mi = 0; mi < 2; ++mi)
#pragma unroll
          for (int nv = 0; nv < 4; ++nv)
            acc_r2[mi][nv] = mfma_bf16(pf[mi], vf[nv], acc_r2[mi][nv]);
      }
    }
    __syncthreads();
  }

  // epilogue: mix softmax(w_mix), normalize, store bf16 ctx in [B,S,H*DH]
  float w0 = wmix[0], w1 = wmix[1];
  float e0 = __expf(w0), e1 = __expf(w1);
  float mix0 = e0 / (e0 + e1), mix1 = e1 / (e0 + e1);

  float linv[2][4];
#pragma unroll
  for (int mi = 0; mi < 2; ++mi)
#pragma unroll
    for (int r = 0; r < 4; ++r) {
      float v = lp[mi][r];
      v += __shfl_xor(v, 1);
      v += __shfl_xor(v, 2);
      v += __shfl_xor(v, 4);
      v += __shfl_xor(v, 8);
      linv[mi][r] = 1.0f / v;
    }

#pragma unroll
  for (int mi = 0; mi < 2; ++mi)
#pragma unroll
    for (int nv = 0; nv < 4; ++nv)
#pragma unroll
      for (int r = 0; r < 4; ++r) {
        int srow = qt * 128 + wave * 32 + mi * 16 + quad * 4 + r;
        int col = h * 64 + nv * 16 + l16;
        float v = mix0 * acc_s[mi][nv][r] * linv[mi][r] + mix1 * acc_r2[mi][nv][r];
        Ctx[(size_t)(b * Sn + srow) * Dm + col] = f32_to_bf16(v);
      }
}

// ---------------- output projection GEMM (fp32 out) ----------------
__global__ __launch_bounds__(256, 3) void k_gemm_out(
    const unsigned short* __restrict__ Abf, const unsigned short* __restrict__ W,
    const float* __restrict__ bias, float* __restrict__ out) {
  __shared__ unsigned short As[128 * 32];
  __shared__ unsigned short Bs[128 * 32];

  const int tid = threadIdx.x;
  const int wave = tid >> 6, lane = tid & 63;
  const int wm = wave >> 1, wn = wave & 1;
  const int quad = lane >> 4, l16 = lane & 15;
  const int bm = blockIdx.y * 128, bn = blockIdx.x * 128;

  const int sr = lane >> 2;
  const int sc = (lane & 3) * 8;
  const unsigned short* gA0 = Abf + (size_t)(bm + (wave * 2 + 0) * 16 + sr) * Dm + sc;
  const unsigned short* gA1 = Abf + (size_t)(bm + (wave * 2 + 1) * 16 + sr) * Dm + sc;
  const unsigned short* gB0 = W + (size_t)(bn + (wave * 2 + 0) * 16 + sr) * Dm + sc;
  const unsigned short* gB1 = W + (size_t)(bn + (wave * 2 + 1) * 16 + sr) * Dm + sc;
  unsigned short* lA0 = &As[(wave * 2 + 0) * 512];
  unsigned short* lA1 = &As[(wave * 2 + 1) * 512];
  unsigned short* lB0 = &Bs[(wave * 2 + 0) * 512];
  unsigned short* lB1 = &Bs[(wave * 2 + 1) * 512];

  f32x4 acc[4][4];
#pragma unroll
  for (int i = 0; i < 4; ++i)
#pragma unroll
    for (int j = 0; j < 4; ++j)
#pragma unroll
      for (int r = 0; r < 4; ++r) acc[i][j][r] = 0.f;

  for (int kk = 0; kk < Dm; kk += 32) {
    gload_lds16(gA0 + kk, lA0);
    gload_lds16(gA1 + kk, lA1);
    gload_lds16(gB0 + kk, lB0);
    gload_lds16(gB1 + kk, lB1);
    __syncthreads();
    short8 af[4], bf[4];
#pragma unroll
    for (int mi = 0; mi < 4; ++mi)
      af[mi] = *(const short8*)(&As[(wm * 64 + mi * 16 + l16) * 32 + quad * 8]);
#pragma unroll
    for (int ni = 0; ni < 4; ++ni)
      bf[ni] = *(const short8*)(&Bs[(wn * 64 + ni * 16 + l16) * 32 + quad * 8]);
#pragma unroll
    for (int mi = 0; mi < 4; ++mi)
#pragma unroll
      for (int ni = 0; ni < 4; ++ni)
        acc[mi][ni] = mfma_bf16(af[mi], bf[ni], acc[mi][ni]);
    __syncthreads();
  }

#pragma unroll
  for (int ni = 0; ni < 4; ++ni) {
    int n = bn + wn * 64 + ni * 16 + l16;
    float bias_v = bias[n];
#pragma unroll
    for (int mi = 0; mi < 4; ++mi) {
#pragma unroll
      for (int r = 0; r < 4; ++r) {
        int m = bm + wm * 64 + mi * 16 + quad * 4 + r;
        out[(size_t)m * Dm + n] = acc[mi][ni][r] + bias_v;
      }
    }
  }
}

extern "C" void kernel_launch(void* const* d_in, const int* in_sizes, int n_in,
                              void* d_out, int out_size, void* d_ws, size_t ws_size,
                              hipStream_t stream) {
  const float* hs = (const float*)d_in[0];
  const float* Wq = (const float*)d_in[1];
  const float* bq = (const float*)d_in[2];
  const float* Wk = (const float*)d_in[3];
  const float* bk = (const float*)d_in[4];
  const float* Wv = (const float*)d_in[5];
  const float* bv = (const float*)d_in[6];
  const float* Wo = (const float*)d_in[7];
  const float* bo = (const float*)d_in[8];
  const float* wmix = (const float*)d_in[9];

  // ws layout (bf16/ushort elements); Ctx aliases hbf (hbf dead after QKV GEMM)
  unsigned short* hbf = (unsigned short*)d_ws;          // 8192*768
  unsigned short* wbf = hbf + (size_t)Mn * Dm;          // 4*768*768
  unsigned short* Qb  = wbf + (size_t)4 * Dm * Dm;      // 8192*768
  unsigned short* Kb  = Qb + (size_t)Mn * Dm;           // 8192*768
  unsigned short* Vt  = Kb + (size_t)Mn * Dm;           // 48*64*2048 == 8192*768
  unsigned short* Ctx = hbf;                            // reuse

  k_cast_hidden<<<dim3(6144), dim3(256), 0, stream>>>(hs, hbf);
  k_cast_w<<<dim3(576, 4), dim3(256), 0, stream>>>(Wq, Wk, Wv, Wo, wbf);
  k_gemm_qkv<<<dim3(6, 64, 3), dim3(256), 0, stream>>>(hbf, wbf, bq, bk, bv, Qb, Kb, Vt);
  k_attn<<<dim3(16, 48), dim3(256), 0, stream>>>(Qb, Kb, Vt, wmix, Ctx);
  k_gemm_out<<<dim3(6, 64), dim3(256), 0, stream>>>(Ctx, wbf + (size_t)3 * Dm * Dm, bo,
                                                    (float*)d_out);
}

// Round 2
// 354.014 us; speedup vs baseline: 1.1367x; 1.1367x over previous
//
#include <hip/hip_runtime.h>

#define DEV __device__ __forceinline__

typedef __attribute__((ext_vector_type(8))) short short8;
typedef __attribute__((ext_vector_type(4))) float f32x4;

constexpr int Dm = 768;   // model dim
constexpr int Sn = 2048;  // seq len
constexpr int Bn = 4;     // batch
constexpr int Hn = 12;    // heads
constexpr int Mn = Bn * Sn;  // 8192 rows

// Q is pre-scaled by 0.125*log2(e) so scores come out as s*log2(e):
// p1 = exp2(sacc) = e^s ; p2 = relu(sacc)^2 = (log2e)^2 * relu(s)^2
constexpr float kQScale = 0.18033688011112043f;     // 0.125 * log2(e)
constexpr float kR2Fix  = 0.4804530139182014f;      // 1 / (log2(e))^2

DEV unsigned short f32_to_bf16(float f) {
  unsigned int u = __float_as_uint(f);
  u = (u + 0x7fffu + ((u >> 16) & 1u)) >> 16;
  return (unsigned short)u;
}

// pack two floats to bf16 pair: result low16=bf16(lo), high16=bf16(hi)
DEV unsigned pack_bf16(float hi, float lo) {
  return __builtin_amdgcn_perm(__float_as_uint(hi) + 0x8000u,
                               __float_as_uint(lo) + 0x8000u, 0x07060302u);
}

DEV f32x4 mfma_bf16(short8 a, short8 b, f32x4 c) {
  return __builtin_amdgcn_mfma_f32_16x16x32_bf16(a, b, c, 0, 0, 0);
}

// async global->LDS, 16B per lane; LDS dest = wave-uniform base + lane*16
DEV void gload_lds16(const void* g, void* l) {
  __builtin_amdgcn_global_load_lds(
      (__attribute__((address_space(1))) const unsigned int*)g,
      (__attribute__((address_space(3))) unsigned int*)l, 16, 0, 0);
}

// ---------------- cast kernels ----------------
__global__ __launch_bounds__(256) void k_cast_hidden(const float* __restrict__ src,
                                                     unsigned short* __restrict__ dst) {
  int i = blockIdx.x * 256 + threadIdx.x;
  float4 v = ((const float4*)src)[i];
  ushort4 o;
  o.x = f32_to_bf16(v.x); o.y = f32_to_bf16(v.y);
  o.z = f32_to_bf16(v.z); o.w = f32_to_bf16(v.w);
  ((ushort4*)dst)[i] = o;
}

__global__ __launch_bounds__(256) void k_cast_w(const float* __restrict__ Wq,
                                                const float* __restrict__ Wk,
                                                const float* __restrict__ Wv,
                                                const float* __restrict__ Wo,
                                                unsigned short* __restrict__ wbf) {
  const float* src = (blockIdx.y == 0) ? Wq : (blockIdx.y == 1) ? Wk
                   : (blockIdx.y == 2) ? Wv : Wo;
  unsigned short* dst = wbf + (size_t)blockIdx.y * (Dm * Dm);
  int i = blockIdx.x * 256 + threadIdx.x;
  float4 v = ((const float4*)src)[i];
  ushort4 o;
  o.x = f32_to_bf16(v.x); o.y = f32_to_bf16(v.y);
  o.z = f32_to_bf16(v.z); o.w = f32_to_bf16(v.w);
  ((ushort4*)dst)[i] = o;
}

// ---------------- QKV projection GEMM ----------------
// C[M,N] = A[M,K] * W[N,K]^T + bias ; z=0->Q (pre-scaled), z=1->K, z=2->V transposed
__global__ __launch_bounds__(256, 3) void k_gemm_qkv(
    const unsigned short* __restrict__ Abf, const unsigned short* __restrict__ wbf,
    const float* __restrict__ bq, const float* __restrict__ bk, const float* __restrict__ bv,
    unsigned short* __restrict__ Qb, unsigned short* __restrict__ Kb,
    unsigned short* __restrict__ Vt) {
  __shared__ unsigned short As[128 * 32];
  __shared__ unsigned short Bs[128 * 32];

  const int tid = threadIdx.x;
  const int wave = tid >> 6, lane = tid & 63;
  const int wm = wave >> 1, wn = wave & 1;
  const int quad = lane >> 4, l16 = lane & 15;
  const int bm = blockIdx.y * 128, bn = blockIdx.x * 128;
  const int z = blockIdx.z;

  const unsigned short* W = wbf + (size_t)z * (Dm * Dm);
  const float* bias = (z == 0) ? bq : ((z == 1) ? bk : bv);

  const int sr = lane >> 2;
  const int sc = (lane & 3) * 8;
  const unsigned short* gA0 = Abf + (size_t)(bm + (wave * 2 + 0) * 16 + sr) * Dm + sc;
  const unsigned short* gA1 = Abf + (size_t)(bm + (wave * 2 + 1) * 16 + sr) * Dm + sc;
  const unsigned short* gB0 = W + (size_t)(bn + (wave * 2 + 0) * 16 + sr) * Dm + sc;
  const unsigned short* gB1 = W + (size_t)(bn + (wave * 2 + 1) * 16 + sr) * Dm + sc;
  unsigned short* lA0 = &As[(wave * 2 + 0) * 512];
  unsigned short* lA1 = &As[(wave * 2 + 1) * 512];
  unsigned short* lB0 = &Bs[(wave * 2 + 0) * 512];
  unsigned short* lB1 = &Bs[(wave * 2 + 1) * 512];

  f32x4 acc[4][4];
#pragma unroll
  for (int i = 0; i < 4; ++i)
#pragma unroll
    for (int j = 0; j < 4; ++j)
#pragma unroll
      for (int r = 0; r < 4; ++r) acc[i][j][r] = 0.f;

  for (int kk = 0; kk < Dm; kk += 32) {
    gload_lds16(gA0 + kk, lA0);
    gload_lds16(gA1 + kk, lA1);
    gload_lds16(gB0 + kk, lB0);
    gload_lds16(gB1 + kk, lB1);
    __syncthreads();
    short8 af[4], bf[4];
#pragma unroll
    for (int mi = 0; mi < 4; ++mi)
      af[mi] = *(const short8*)(&As[(wm * 64 + mi * 16 + l16) * 32 + quad * 8]);
#pragma unroll
    for (int ni = 0; ni < 4; ++ni)
      bf[ni] = *(const short8*)(&Bs[(wn * 64 + ni * 16 + l16) * 32 + quad * 8]);
#pragma unroll
    for (int mi = 0; mi < 4; ++mi)
#pragma unroll
      for (int ni = 0; ni < 4; ++ni)
        acc[mi][ni] = mfma_bf16(af[mi], bf[ni], acc[mi][ni]);
    __syncthreads();
  }

#pragma unroll
  for (int ni = 0; ni < 4; ++ni) {
    int n = bn + wn * 64 + ni * 16 + l16;
    float bias_v = bias[n];
    int h = n >> 6, dcol = n & 63;
#pragma unroll
    for (int mi = 0; mi < 4; ++mi) {
#pragma unroll
      for (int r = 0; r < 4; ++r) {
        int m = bm + wm * 64 + mi * 16 + quad * 4 + r;
        float val = acc[mi][ni][r] + bias_v;
        if (z == 0) {
          Qb[(size_t)m * Dm + n] = f32_to_bf16(val * kQScale);
        } else if (z == 1) {
          Kb[(size_t)m * Dm + n] = f32_to_bf16(val);
        } else {
          int b = m >> 11, s = m & 2047;
          Vt[((size_t)((b * Hn + h) * 64 + dcol)) * Sn + s] = f32_to_bf16(val);
        }
      }
    }
  }
}

// ---------------- flash attention (mixed softmax + relu^2) ----------------
// LDS layouts XOR-swizzled in 16B chunks so both DMA staging and b128 frag
// reads are conflict-free:
//   Ks[r][c]  (128x64 shorts): off = r*64  + (((c>>3) ^ (r&7))  <<3) + (c&7)
//   Vs[d][s]  (64x128 shorts): off = d*128 + (((s>>3) ^ (d&15)) <<3) + (s&7)
//   P[q][k]   (32x64 shorts, per wave): off = q*64 + (((k>>3) ^ (q&7))<<3) + (k&7)
__global__ __launch_bounds__(256, 2) void k_attn(
    const unsigned short* __restrict__ Qb, const unsigned short* __restrict__ Kb,
    const unsigned short* __restrict__ Vt, const float* __restrict__ wmix,
    unsigned short* __restrict__ Ctx) {
  __shared__ unsigned short Ks[128 * 64];
  __shared__ unsigned short Vs[64 * 128];
  __shared__ unsigned short Ps1[4 * 32 * 64];
  __shared__ unsigned short Ps2[4 * 32 * 64];

  const int tid = threadIdx.x;
  const int wave = tid >> 6, lane = tid & 63;
  const int quad = lane >> 4, l16 = lane & 15;
  const int l8 = l16 & 7;
  const int qt = blockIdx.x;   // 16 q-tiles
  const int bh = blockIdx.y;   // 48 = B*H
  const int b = bh / Hn, h = bh % Hn;

  const unsigned short* Qg = Qb + (size_t)(b * Sn + qt * 128) * Dm + h * 64;
  const unsigned short* Kg = Kb + (size_t)(b * Sn) * Dm + h * 64;
  const unsigned short* Vg = Vt + (size_t)bh * 64 * Sn;

  // DMA lane decode: K-style 1KB block = 8 rows x 8 chunks
  const int krr = lane >> 3, kcc = lane & 7;
  const int kchunk = kcc ^ krr;  // logical 16B chunk this lane fetches
  // V-style 1KB block = 4 rows x 16 chunks
  const int vrr = lane >> 4, vcc = lane & 15;

  // ---- stage Q tile into Ks via DMA, pull A-frags ----
#pragma unroll
  for (int i = 0; i < 4; ++i) {
    int t = wave * 4 + i;
    gload_lds16(Qg + (size_t)(t * 8 + krr) * Dm + kchunk * 8, &Ks[t * 512]);
  }
  __syncthreads();
  short8 qf[2][2];
#pragma unroll
  for (int mi = 0; mi < 2; ++mi)
#pragma unroll
    for (int ks = 0; ks < 2; ++ks)
      qf[mi][ks] = *(const short8*)(
          &Ks[(wave * 32 + mi * 16 + l16) * 64 + (((ks * 4 + quad) ^ l8) << 3)]);
  __syncthreads();

  f32x4 acc_s[2][4], acc_r2[2][4];
#pragma unroll
  for (int i = 0; i < 2; ++i)
#pragma unroll
    for (int j = 0; j < 4; ++j)
#pragma unroll
      for (int r = 0; r < 4; ++r) { acc_s[i][j][r] = 0.f; acc_r2[i][j][r] = 0.f; }
  float lp[2][4] = {{0.f, 0.f, 0.f, 0.f}, {0.f, 0.f, 0.f, 0.f}};

  unsigned short* P1 = &Ps1[wave * 2048];
  unsigned short* P2 = &Ps2[wave * 2048];

  for (int kt = 0; kt < 16; ++kt) {
    // stage K tile + V^T tile via DMA
#pragma unroll
    for (int i = 0; i < 4; ++i) {
      int t = wave * 4 + i;
      gload_lds16(Kg + (size_t)(kt * 128 + t * 8 + krr) * Dm + kchunk * 8, &Ks[t * 512]);
    }
#pragma unroll
    for (int i = 0; i < 4; ++i) {
      int t = wave * 4 + i;
      int vrow = t * 4 + vrr;
      int vch = vcc ^ ((4 * i + vrr) & 15);
      gload_lds16(Vg + (size_t)vrow * Sn + kt * 128 + vch * 8, &Vs[t * 512]);
    }
    __syncthreads();

    // QK^T: wave computes 32 q-rows x 128 k-cols (scores already *log2e/8 via Q scale)
    f32x4 sacc[2][8];
#pragma unroll
    for (int i = 0; i < 2; ++i)
#pragma unroll
      for (int j = 0; j < 8; ++j)
#pragma unroll
        for (int r = 0; r < 4; ++r) sacc[i][j][r] = 0.f;
#pragma unroll
    for (int ks = 0; ks < 2; ++ks) {
      short8 kf[8];
#pragma unroll
      for (int ni = 0; ni < 8; ++ni)
        kf[ni] = *(const short8*)(
            &Ks[(ni * 16 + l16) * 64 + (((ks * 4 + quad) ^ l8) << 3)]);
#pragma unroll
      for (int mi = 0; mi < 2; ++mi)
#pragma unroll
        for (int ni = 0; ni < 8; ++ni)
          sacc[mi][ni] = mfma_bf16(qf[mi][ks], kf[ni], sacc[mi][ni]);
    }

#pragma unroll
    for (int half = 0; half < 2; ++half) {
      // single elementwise pass: p1 = exp2(s), p2 = relu(s)^2 (unscaled)
#pragma unroll
      for (int mi = 0; mi < 2; ++mi) {
        const int qbase = mi * 16 + quad * 4;
#pragma unroll
        for (int nj = 0; nj < 4; ++nj) {
          f32x4 sv = sacc[mi][half * 4 + nj];
          float p1v[4], p2v[4];
#pragma unroll
          for (int r = 0; r < 4; ++r) {
            p1v[r] = __builtin_amdgcn_exp2f(sv[r]);
            lp[mi][r] += p1v[r];
            float t = fmaxf(sv[r], 0.f);
            p2v[r] = t * t;
          }
          const int chunk = nj * 2 + (l16 >> 3);
#pragma unroll
          for (int rp = 0; rp < 2; ++rp) {
            unsigned u1 = pack_bf16(p1v[rp * 2 + 1], p1v[rp * 2]);
            unsigned u2 = pack_bf16(p2v[rp * 2 + 1], p2v[rp * 2]);
            int q0 = qbase + rp * 2, q1 = q0 + 1;
            int o0 = q0 * 64 + ((chunk ^ (q0 & 7)) << 3) + l8;
            int o1 = q1 * 64 + ((chunk ^ (q1 & 7)) << 3) + l8;
            P1[o0] = (unsigned short)u1;
            P1[o1] = (unsigned short)(u1 >> 16);
            P2[o0] = (unsigned short)u2;
            P2[o1] = (unsigned short)(u2 >> 16);
          }
        }
      }
      // PV: load vf once, feed both accumulators
#pragma unroll
      for (int ks = 0; ks < 2; ++ks) {
        short8 vf[4], pf1[2], pf2[2];
#pragma unroll
        for (int nv = 0; nv < 4; ++nv)
          vf[nv] = *(const short8*)(
              &Vs[(nv * 16 + l16) * 128 + (((half * 8 + ks * 4 + quad) ^ l16) << 3)]);
#pragma unroll
        for (int mi = 0; mi < 2; ++mi) {
          pf1[mi] = *(const short8*)(
              &P1[(mi * 16 + l16) * 64 + (((ks * 4 + quad) ^ l8) << 3)]);
          pf2[mi] = *(const short8*)(
              &P2[(mi * 16 + l16) * 64 + (((ks * 4 + quad) ^ l8) << 3)]);
        }
#pragma unroll
        for (int mi = 0; mi < 2; ++mi)
#pragma unroll
          for (int nv = 0; nv < 4; ++nv) {
            acc_s[mi][nv] = mfma_bf16(pf1[mi], vf[nv], acc_s[mi][nv]);
            acc_r2[mi][nv] = mfma_bf16(pf2[mi], vf[nv], acc_r2[mi][nv]);
          }
      }
    }
    __syncthreads();
  }

  // epilogue: mix softmax(w_mix), normalize, store bf16 ctx in [B,S,H*DH]
  float w0 = wmix[0], w1 = wmix[1];
  float e0 = __expf(w0), e1 = __expf(w1);
  float mix0 = e0 / (e0 + e1);
  float mix1 = (e1 / (e0 + e1)) * kR2Fix;  // undo (log2e)^2 in relu^2 branch

  float linv[2][4];
#pragma unroll
  for (int mi = 0; mi < 2; ++mi)
#pragma unroll
    for (int r = 0; r < 4; ++r) {
      float v = lp[mi][r];
      v += __shfl_xor(v, 1);
      v += __shfl_xor(v, 2);
      v += __shfl_xor(v, 4);
      v += __shfl_xor(v, 8);
      linv[mi][r] = 1.0f / v;
    }

#pragma unroll
  for (int mi = 0; mi < 2; ++mi)
#pragma unroll
    for (int nv = 0; nv < 4; ++nv)
#pragma unroll
      for (int r = 0; r < 4; ++r) {
        int srow = qt * 128 + wave * 32 + mi * 16 + quad * 4 + r;
        int col = h * 64 + nv * 16 + l16;
        float v = mix0 * acc_s[mi][nv][r] * linv[mi][r] + mix1 * acc_r2[mi][nv][r];
        Ctx[(size_t)(b * Sn + srow) * Dm + col] = f32_to_bf16(v);
      }
}

// ---------------- output projection GEMM (fp32 out) ----------------
__global__ __launch_bounds__(256, 3) void k_gemm_out(
    const unsigned short* __restrict__ Abf, const unsigned short* __restrict__ W,
    const float* __restrict__ bias, float* __restrict__ out) {
  __shared__ unsigned short As[128 * 32];
  __shared__ unsigned short Bs[128 * 32];

  const int tid = threadIdx.x;
  const int wave = tid >> 6, lane = tid & 63;
  const int wm = wave >> 1, wn = wave & 1;
  const int quad = lane >> 4, l16 = lane & 15;
  const int bm = blockIdx.y * 128, bn = blockIdx.x * 128;

  const int sr = lane >> 2;
  const int sc = (lane & 3) * 8;
  const unsigned short* gA0 = Abf + (size_t)(bm + (wave * 2 + 0) * 16 + sr) * Dm + sc;
  const unsigned short* gA1 = Abf + (size_t)(bm + (wave * 2 + 1) * 16 + sr) * Dm + sc;
  const unsigned short* gB0 = W + (size_t)(bn + (wave * 2 + 0) * 16 + sr) * Dm + sc;
  const unsigned short* gB1 = W + (size_t)(bn + (wave * 2 + 1) * 16 + sr) * Dm + sc;
  unsigned short* lA0 = &As[(wave * 2 + 0) * 512];
  unsigned short* lA1 = &As[(wave * 2 + 1) * 512];
  unsigned short* lB0 = &Bs[(wave * 2 + 0) * 512];
  unsigned short* lB1 = &Bs[(wave * 2 + 1) * 512];

  f32x4 acc[4][4];
#pragma unroll
  for (int i = 0; i < 4; ++i)
#pragma unroll
    for (int j = 0; j < 4; ++j)
#pragma unroll
      for (int r = 0; r < 4; ++r) acc[i][j][r] = 0.f;

  for (int kk = 0; kk < Dm; kk += 32) {
    gload_lds16(gA0 + kk, lA0);
    gload_lds16(gA1 + kk, lA1);
    gload_lds16(gB0 + kk, lB0);
    gload_lds16(gB1 + kk, lB1);
    __syncthreads();
    short8 af[4], bf[4];
#pragma unroll
    for (int mi = 0; mi < 4; ++mi)
      af[mi] = *(const short8*)(&As[(wm * 64 + mi * 16 + l16) * 32 + quad * 8]);
#pragma unroll
    for (int ni = 0; ni < 4; ++ni)
      bf[ni] = *(const short8*)(&Bs[(wn * 64 + ni * 16 + l16) * 32 + quad * 8]);
#pragma unroll
    for (int mi = 0; mi < 4; ++mi)
#pragma unroll
      for (int ni = 0; ni < 4; ++ni)
        acc[mi][ni] = mfma_bf16(af[mi], bf[ni], acc[mi][ni]);
    __syncthreads();
  }

#pragma unroll
  for (int ni = 0; ni < 4; ++ni) {
    int n = bn + wn * 64 + ni * 16 + l16;
    float bias_v = bias[n];
#pragma unroll
    for (int mi = 0; mi < 4; ++mi) {
#pragma unroll
      for (int r = 0; r < 4; ++r) {
        int m = bm + wm * 64 + mi * 16 + quad * 4 + r;
        out[(size_t)m * Dm + n] = acc[mi][ni][r] + bias_v;
      }
    }
  }
}

extern "C" void kernel_launch(void* const* d_in, const int* in_sizes, int n_in,
                              void* d_out, int out_size, void* d_ws, size_t ws_size,
                              hipStream_t stream) {
  const float* hs = (const float*)d_in[0];
  const float* Wq = (const float*)d_in[1];
  const float* bq = (const float*)d_in[2];
  const float* Wk = (const float*)d_in[3];
  const float* bk = (const float*)d_in[4];
  const float* Wv = (const float*)d_in[5];
  const float* bv = (const float*)d_in[6];
  const float* Wo = (const float*)d_in[7];
  const float* bo = (const float*)d_in[8];
  const float* wmix = (const float*)d_in[9];

  unsigned short* hbf = (unsigned short*)d_ws;          // 8192*768
  unsigned short* wbf = hbf + (size_t)Mn * Dm;          // 4*768*768
  unsigned short* Qb  = wbf + (size_t)4 * Dm * Dm;      // 8192*768
  unsigned short* Kb  = Qb + (size_t)Mn * Dm;           // 8192*768
  unsigned short* Vt  = Kb + (size_t)Mn * Dm;           // 48*64*2048
  unsigned short* Ctx = hbf;                            // reuse (hbf dead after QKV)

  k_cast_hidden<<<dim3(6144), dim3(256), 0, stream>>>(hs, hbf);
  k_cast_w<<<dim3(576, 4), dim3(256), 0, stream>>>(Wq, Wk, Wv, Wo, wbf);
  k_gemm_qkv<<<dim3(6, 64, 3), dim3(256), 0, stream>>>(hbf, wbf, bq, bk, bv, Qb, Kb, Vt);
  k_attn<<<dim3(16, 48), dim3(256), 0, stream>>>(Qb, Kb, Vt, wmix, Ctx);
  k_gemm_out<<<dim3(6, 64), dim3(256), 0, stream>>>(Ctx, wbf + (size_t)3 * Dm * Dm, bo,
                                                    (float*)d_out);
}

// Round 3
// 294.213 us; speedup vs baseline: 1.3678x; 1.2033x over previous
//
#include <hip/hip_runtime.h>

#define DEV __device__ __forceinline__

typedef __attribute__((ext_vector_type(8))) short short8;
typedef __attribute__((ext_vector_type(4))) float f32x4;
typedef __attribute__((ext_vector_type(2))) unsigned int u32x2;
typedef __attribute__((ext_vector_type(4))) unsigned int u32x4;

constexpr int Dm = 768;   // model dim
constexpr int Sn = 2048;  // seq len
constexpr int Bn = 4;     // batch
constexpr int Hn = 12;    // heads
constexpr int Mn = Bn * Sn;  // 8192 rows

// Q is pre-scaled by 0.125*log2(e) so scores come out as s*log2(e):
// p1 = exp2(sacc) = e^s ; p2 = relu(sacc)^2 = (log2e)^2 * relu(s)^2
constexpr float kQScale = 0.18033688011112043f;     // 0.125 * log2(e)
constexpr float kR2Fix  = 0.4804530139182014f;      // 1 / (log2(e))^2

DEV unsigned short f32_to_bf16(float f) {
  unsigned int u = __float_as_uint(f);
  u = (u + 0x7fffu + ((u >> 16) & 1u)) >> 16;
  return (unsigned short)u;
}

// pack two floats to bf16 pair: result low16=bf16(lo), high16=bf16(hi), RNE-ish
DEV unsigned pack_bf16(float hi, float lo) {
  return __builtin_amdgcn_perm(__float_as_uint(hi) + 0x8000u,
                               __float_as_uint(lo) + 0x8000u, 0x07060302u);
}

DEV f32x4 mfma_bf16(short8 a, short8 b, f32x4 c) {
  return __builtin_amdgcn_mfma_f32_16x16x32_bf16(a, b, c, 0, 0, 0);
}

// async global->LDS, 16B per lane; LDS dest = wave-uniform base + lane*16
DEV void gload_lds16(const void* g, void* l) {
  __builtin_amdgcn_global_load_lds(
      (__attribute__((address_space(1))) const unsigned int*)g,
      (__attribute__((address_space(3))) unsigned int*)l, 16, 0, 0);
}

// Transform two 16x16 S^T C-layout tiles (packed as bf16 dwords) into one
// B-operand fragment for mfma_16x16x32 (K=32 keys spanning both tiles).
// xd*: tile keys [0,16) (dword0 = r0,r1 ; dword1 = r2,r3), yd*: keys [16,32).
DEV short8 transpose_to_bfrag(unsigned xd0, unsigned xd1, unsigned yd0, unsigned yd1) {
  u32x2 a0 = __builtin_amdgcn_permlane32_swap(xd0, yd0, false, false);
  u32x2 b0 = __builtin_amdgcn_permlane16_swap(a0[0], a0[1], false, false);
  u32x2 a1 = __builtin_amdgcn_permlane32_swap(xd1, yd1, false, false);
  u32x2 b1 = __builtin_amdgcn_permlane16_swap(a1[0], a1[1], false, false);
  u32x4 f = {b0[0], b1[0], b0[1], b1[1]};
  return __builtin_bit_cast(short8, f);
}

// ---------------- cast kernels ----------------
__global__ __launch_bounds__(256) void k_cast_hidden(const float* __restrict__ src,
                                                     unsigned short* __restrict__ dst) {
  int i = blockIdx.x * 256 + threadIdx.x;
  float4 v = ((const float4*)src)[i];
  ushort4 o;
  o.x = f32_to_bf16(v.x); o.y = f32_to_bf16(v.y);
  o.z = f32_to_bf16(v.z); o.w = f32_to_bf16(v.w);
  ((ushort4*)dst)[i] = o;
}

__global__ __launch_bounds__(256) void k_cast_w(const float* __restrict__ Wq,
                                                const float* __restrict__ Wk,
                                                const float* __restrict__ Wv,
                                                const float* __restrict__ Wo,
                                                unsigned short* __restrict__ wbf) {
  const float* src = (blockIdx.y == 0) ? Wq : (blockIdx.y == 1) ? Wk
                   : (blockIdx.y == 2) ? Wv : Wo;
  unsigned short* dst = wbf + (size_t)blockIdx.y * (Dm * Dm);
  int i = blockIdx.x * 256 + threadIdx.x;
  float4 v = ((const float4*)src)[i];
  ushort4 o;
  o.x = f32_to_bf16(v.x); o.y = f32_to_bf16(v.y);
  o.z = f32_to_bf16(v.z); o.w = f32_to_bf16(v.w);
  ((ushort4*)dst)[i] = o;
}

// ---------------- QKV projection GEMM ----------------
// C[M,N] = A[M,K] * W[N,K]^T + bias ; z=0->Q (pre-scaled), z=1->K, z=2->V transposed
__global__ __launch_bounds__(256, 3) void k_gemm_qkv(
    const unsigned short* __restrict__ Abf, const unsigned short* __restrict__ wbf,
    const float* __restrict__ bq, const float* __restrict__ bk, const float* __restrict__ bv,
    unsigned short* __restrict__ Qb, unsigned short* __restrict__ Kb,
    unsigned short* __restrict__ Vt) {
  __shared__ unsigned short As[128 * 32];
  __shared__ unsigned short Bs[128 * 32];

  const int tid = threadIdx.x;
  const int wave = tid >> 6, lane = tid & 63;
  const int wm = wave >> 1, wn = wave & 1;
  const int quad = lane >> 4, l16 = lane & 15;
  const int bm = blockIdx.y * 128, bn = blockIdx.x * 128;
  const int z = blockIdx.z;

  const unsigned short* W = wbf + (size_t)z * (Dm * Dm);
  const float* bias = (z == 0) ? bq : ((z == 1) ? bk : bv);

  const int sr = lane >> 2;
  const int sc = (lane & 3) * 8;
  const unsigned short* gA0 = Abf + (size_t)(bm + (wave * 2 + 0) * 16 + sr) * Dm + sc;
  const unsigned short* gA1 = Abf + (size_t)(bm + (wave * 2 + 1) * 16 + sr) * Dm + sc;
  const unsigned short* gB0 = W + (size_t)(bn + (wave * 2 + 0) * 16 + sr) * Dm + sc;
  const unsigned short* gB1 = W + (size_t)(bn + (wave * 2 + 1) * 16 + sr) * Dm + sc;
  unsigned short* lA0 = &As[(wave * 2 + 0) * 512];
  unsigned short* lA1 = &As[(wave * 2 + 1) * 512];
  unsigned short* lB0 = &Bs[(wave * 2 + 0) * 512];
  unsigned short* lB1 = &Bs[(wave * 2 + 1) * 512];

  f32x4 acc[4][4];
#pragma unroll
  for (int i = 0; i < 4; ++i)
#pragma unroll
    for (int j = 0; j < 4; ++j)
#pragma unroll
      for (int r = 0; r < 4; ++r) acc[i][j][r] = 0.f;

  for (int kk = 0; kk < Dm; kk += 32) {
    gload_lds16(gA0 + kk, lA0);
    gload_lds16(gA1 + kk, lA1);
    gload_lds16(gB0 + kk, lB0);
    gload_lds16(gB1 + kk, lB1);
    __syncthreads();
    short8 af[4], bf[4];
#pragma unroll
    for (int mi = 0; mi < 4; ++mi)
      af[mi] = *(const short8*)(&As[(wm * 64 + mi * 16 + l16) * 32 + quad * 8]);
#pragma unroll
    for (int ni = 0; ni < 4; ++ni)
      bf[ni] = *(const short8*)(&Bs[(wn * 64 + ni * 16 + l16) * 32 + quad * 8]);
#pragma unroll
    for (int mi = 0; mi < 4; ++mi)
#pragma unroll
      for (int ni = 0; ni < 4; ++ni)
        acc[mi][ni] = mfma_bf16(af[mi], bf[ni], acc[mi][ni]);
    __syncthreads();
  }

#pragma unroll
  for (int ni = 0; ni < 4; ++ni) {
    int n = bn + wn * 64 + ni * 16 + l16;
    float bias_v = bias[n];
    int h = n >> 6, dcol = n & 63;
#pragma unroll
    for (int mi = 0; mi < 4; ++mi) {
#pragma unroll
      for (int r = 0; r < 4; ++r) {
        int m = bm + wm * 64 + mi * 16 + quad * 4 + r;
        float val = acc[mi][ni][r] + bias_v;
        if (z == 0) {
          Qb[(size_t)m * Dm + n] = f32_to_bf16(val * kQScale);
        } else if (z == 1) {
          Kb[(size_t)m * Dm + n] = f32_to_bf16(val);
        } else {
          int b = m >> 11, s = m & 2047;
          Vt[((size_t)((b * Hn + h) * 64 + dcol)) * Sn + s] = f32_to_bf16(val);
        }
      }
    }
  }
}

// ---------------- flash attention (mixed softmax + relu^2) ----------------
// Scores computed TRANSPOSED (S^T = K Q^T) so the PV B-operand is built from
// C-layout fragments with permlane swaps — no P round-trip through LDS.
// LDS layouts XOR-swizzled in 16B chunks (conflict-free DMA write + b128 read):
//   Ks[r][c]  (128x64 shorts): off = r*64  + (((c>>3) ^ (r&7))  <<3) + (c&7)
//   Vs[d][s]  (64x128 shorts): off = d*128 + (((s>>3) ^ (d&15)) <<3) + (s&7)
__global__ __launch_bounds__(256, 2) void k_attn(
    const unsigned short* __restrict__ Qb, const unsigned short* __restrict__ Kb,
    const unsigned short* __restrict__ Vt, const float* __restrict__ wmix,
    unsigned short* __restrict__ Ctx) {
  __shared__ unsigned short Ks[128 * 64];
  __shared__ unsigned short Vs[64 * 128];

  const int tid = threadIdx.x;
  const int wave = tid >> 6, lane = tid & 63;
  const int quad = lane >> 4, l16 = lane & 15;
  const int l8 = l16 & 7;
  const int qt = blockIdx.x;   // 16 q-tiles
  const int bh = blockIdx.y;   // 48 = B*H
  const int b = bh / Hn, h = bh % Hn;

  const unsigned short* Qg = Qb + (size_t)(b * Sn + qt * 128) * Dm + h * 64;
  const unsigned short* Kg = Kb + (size_t)(b * Sn) * Dm + h * 64;
  const unsigned short* Vg = Vt + (size_t)bh * 64 * Sn;

  // DMA lane decode: K-style 1KB block = 8 rows x 8 chunks
  const int krr = lane >> 3, kcc = lane & 7;
  const int kchunk = kcc ^ krr;
  // V-style 1KB block = 4 rows x 16 chunks
  const int vrr = lane >> 4, vcc = lane & 15;

  // ---- stage Q tile into Ks via DMA, pull B-frags (q as N dim) ----
#pragma unroll
  for (int i = 0; i < 4; ++i) {
    int t = wave * 4 + i;
    gload_lds16(Qg + (size_t)(t * 8 + krr) * Dm + kchunk * 8, &Ks[t * 512]);
  }
  __syncthreads();
  short8 qf[2][2];
#pragma unroll
  for (int mi = 0; mi < 2; ++mi)
#pragma unroll
    for (int ks = 0; ks < 2; ++ks)
      qf[mi][ks] = *(const short8*)(
          &Ks[(wave * 32 + mi * 16 + l16) * 64 + (((ks * 4 + quad) ^ l8) << 3)]);
  __syncthreads();

  // accumulators hold ctx^T: [dh-tile nv][...] rows=dh, cols=q
  f32x4 acc_s[2][4], acc_r2[2][4];
#pragma unroll
  for (int i = 0; i < 2; ++i)
#pragma unroll
    for (int j = 0; j < 4; ++j)
#pragma unroll
      for (int r = 0; r < 4; ++r) { acc_s[i][j][r] = 0.f; acc_r2[i][j][r] = 0.f; }
  float lp[2] = {0.f, 0.f};  // softmax denom partial, q = wave*32+mi*16+l16

  for (int kt = 0; kt < 16; ++kt) {
    // stage K tile + V^T tile via DMA
#pragma unroll
    for (int i = 0; i < 4; ++i) {
      int t = wave * 4 + i;
      gload_lds16(Kg + (size_t)(kt * 128 + t * 8 + krr) * Dm + kchunk * 8, &Ks[t * 512]);
    }
#pragma unroll
    for (int i = 0; i < 4; ++i) {
      int t = wave * 4 + i;
      int vrow = t * 4 + vrr;
      int vch = vcc ^ ((4 * i + vrr) & 15);
      gload_lds16(Vg + (size_t)vrow * Sn + kt * 128 + vch * 8, &Vs[t * 512]);
    }
    __syncthreads();

    // process 128 keys as 4 chunks of 32
#pragma unroll
    for (int c = 0; c < 4; ++c) {
      // S^T tiles: rows = keys [c*32, c*32+32), cols = q (32 per wave)
      short8 kf[2][2];
#pragma unroll
      for (int t2 = 0; t2 < 2; ++t2)
#pragma unroll
        for (int ks = 0; ks < 2; ++ks)
          kf[t2][ks] = *(const short8*)(
              &Ks[((c * 2 + t2) * 16 + l16) * 64 + (((ks * 4 + quad) ^ l8) << 3)]);

      f32x4 sacc[2][2];
#pragma unroll
      for (int mi = 0; mi < 2; ++mi)
#pragma unroll
        for (int t2 = 0; t2 < 2; ++t2)
#pragma unroll
          for (int r = 0; r < 4; ++r) sacc[mi][t2][r] = 0.f;
#pragma unroll
      for (int mi = 0; mi < 2; ++mi)
#pragma unroll
        for (int t2 = 0; t2 < 2; ++t2)
#pragma unroll
          for (int ks = 0; ks < 2; ++ks)
            sacc[mi][t2] = mfma_bf16(kf[t2][ks], qf[mi][ks], sacc[mi][t2]);

      short8 vf[4];
#pragma unroll
      for (int nv = 0; nv < 4; ++nv)
        vf[nv] = *(const short8*)(
            &Vs[(nv * 16 + l16) * 128 + (((c * 4 + quad) ^ l16) << 3)]);

#pragma unroll
      for (int mi = 0; mi < 2; ++mi) {
        float p1a[4], p1b[4], p2a[4], p2b[4];
#pragma unroll
        for (int r = 0; r < 4; ++r) {
          float s0 = sacc[mi][0][r], s1 = sacc[mi][1][r];
          p1a[r] = __builtin_amdgcn_exp2f(s0);
          p1b[r] = __builtin_amdgcn_exp2f(s1);
          lp[mi] += p1a[r] + p1b[r];
          float t0 = fmaxf(s0, 0.f), t1 = fmaxf(s1, 0.f);
          p2a[r] = t0 * t0;
          p2b[r] = t1 * t1;
        }
        short8 pf1 = transpose_to_bfrag(pack_bf16(p1a[1], p1a[0]), pack_bf16(p1a[3], p1a[2]),
                                        pack_bf16(p1b[1], p1b[0]), pack_bf16(p1b[3], p1b[2]));
        short8 pf2 = transpose_to_bfrag(pack_bf16(p2a[1], p2a[0]), pack_bf16(p2a[3], p2a[2]),
                                        pack_bf16(p2b[1], p2b[0]), pack_bf16(p2b[3], p2b[2]));
#pragma unroll
        for (int nv = 0; nv < 4; ++nv) {
          acc_s[mi][nv] = mfma_bf16(vf[nv], pf1, acc_s[mi][nv]);
          acc_r2[mi][nv] = mfma_bf16(vf[nv], pf2, acc_r2[mi][nv]);
        }
      }
    }
    __syncthreads();
  }

  // epilogue: mix softmax(w_mix), normalize, store bf16 ctx in [B,S,H*DH]
  float w0 = wmix[0], w1 = wmix[1];
  float e0 = __expf(w0), e1 = __expf(w1);
  float mix0 = e0 / (e0 + e1);
  float mix1 = (e1 / (e0 + e1)) * kR2Fix;  // undo (log2e)^2 in relu^2 branch

  float linv[2];
#pragma unroll
  for (int mi = 0; mi < 2; ++mi) {
    float v = lp[mi];
    v += __shfl_xor(v, 16);
    v += __shfl_xor(v, 32);
    linv[mi] = 1.0f / v;
  }

#pragma unroll
  for (int mi = 0; mi < 2; ++mi) {
    int srow = qt * 128 + wave * 32 + mi * 16 + l16;
#pragma unroll
    for (int nv = 0; nv < 4; ++nv) {
      ushort4 o;
      float v0 = mix0 * acc_s[mi][nv][0] * linv[mi] + mix1 * acc_r2[mi][nv][0];
      float v1 = mix0 * acc_s[mi][nv][1] * linv[mi] + mix1 * acc_r2[mi][nv][1];
      float v2 = mix0 * acc_s[mi][nv][2] * linv[mi] + mix1 * acc_r2[mi][nv][2];
      float v3 = mix0 * acc_s[mi][nv][3] * linv[mi] + mix1 * acc_r2[mi][nv][3];
      o.x = f32_to_bf16(v0); o.y = f32_to_bf16(v1);
      o.z = f32_to_bf16(v2); o.w = f32_to_bf16(v3);
      *(ushort4*)(&Ctx[(size_t)(b * Sn + srow) * Dm + h * 64 + nv * 16 + quad * 4]) = o;
    }
  }
}

// ---------------- output projection GEMM (fp32 out) ----------------
__global__ __launch_bounds__(256, 3) void k_gemm_out(
    const unsigned short* __restrict__ Abf, const unsigned short* __restrict__ W,
    const float* __restrict__ bias, float* __restrict__ out) {
  __shared__ unsigned short As[128 * 32];
  __shared__ unsigned short Bs[128 * 32];

  const int tid = threadIdx.x;
  const int wave = tid >> 6, lane = tid & 63;
  const int wm = wave >> 1, wn = wave & 1;
  const int quad = lane >> 4, l16 = lane & 15;
  const int bm = blockIdx.y * 128, bn = blockIdx.x * 128;

  const int sr = lane >> 2;
  const int sc = (lane & 3) * 8;
  const unsigned short* gA0 = Abf + (size_t)(bm + (wave * 2 + 0) * 16 + sr) * Dm + sc;
  const unsigned short* gA1 = Abf + (size_t)(bm + (wave * 2 + 1) * 16 + sr) * Dm + sc;
  const unsigned short* gB0 = W + (size_t)(bn + (wave * 2 + 0) * 16 + sr) * Dm + sc;
  const unsigned short* gB1 = W + (size_t)(bn + (wave * 2 + 1) * 16 + sr) * Dm + sc;
  unsigned short* lA0 = &As[(wave * 2 + 0) * 512];
  unsigned short* lA1 = &As[(wave * 2 + 1) * 512];
  unsigned short* lB0 = &Bs[(wave * 2 + 0) * 512];
  unsigned short* lB1 = &Bs[(wave * 2 + 1) * 512];

  f32x4 acc[4][4];
#pragma unroll
  for (int i = 0; i < 4; ++i)
#pragma unroll
    for (int j = 0; j < 4; ++j)
#pragma unroll
      for (int r = 0; r < 4; ++r) acc[i][j][r] = 0.f;

  for (int kk = 0; kk < Dm; kk += 32) {
    gload_lds16(gA0 + kk, lA0);
    gload_lds16(gA1 + kk, lA1);
    gload_lds16(gB0 + kk, lB0);
    gload_lds16(gB1 + kk, lB1);
    __syncthreads();
    short8 af[4], bf[4];
#pragma unroll
    for (int mi = 0; mi < 4; ++mi)
      af[mi] = *(const short8*)(&As[(wm * 64 + mi * 16 + l16) * 32 + quad * 8]);
#pragma unroll
    for (int ni = 0; ni < 4; ++ni)
      bf[ni] = *(const short8*)(&Bs[(wn * 64 + ni * 16 + l16) * 32 + quad * 8]);
#pragma unroll
    for (int mi = 0; mi < 4; ++mi)
#pragma unroll
      for (int ni = 0; ni < 4; ++ni)
        acc[mi][ni] = mfma_bf16(af[mi], bf[ni], acc[mi][ni]);
    __syncthreads();
  }

#pragma unroll
  for (int ni = 0; ni < 4; ++ni) {
    int n = bn + wn * 64 + ni * 16 + l16;
    float bias_v = bias[n];
#pragma unroll
    for (int mi = 0; mi < 4; ++mi) {
#pragma unroll
      for (int r = 0; r < 4; ++r) {
        int m = bm + wm * 64 + mi * 16 + quad * 4 + r;
        out[(size_t)m * Dm + n] = acc[mi][ni][r] + bias_v;
      }
    }
  }
}

extern "C" void kernel_launch(void* const* d_in, const int* in_sizes, int n_in,
                              void* d_out, int out_size, void* d_ws, size_t ws_size,
                              hipStream_t stream) {
  const float* hs = (const float*)d_in[0];
  const float* Wq = (const float*)d_in[1];
  const float* bq = (const float*)d_in[2];
  const float* Wk = (const float*)d_in[3];
  const float* bk = (const float*)d_in[4];
  const float* Wv = (const float*)d_in[5];
  const float* bv = (const float*)d_in[6];
  const float* Wo = (const float*)d_in[7];
  const float* bo = (const float*)d_in[8];
  const float* wmix = (const float*)d_in[9];

  unsigned short* hbf = (unsigned short*)d_ws;          // 8192*768
  unsigned short* wbf = hbf + (size_t)Mn * Dm;          // 4*768*768
  unsigned short* Qb  = wbf + (size_t)4 * Dm * Dm;      // 8192*768
  unsigned short* Kb  = Qb + (size_t)Mn * Dm;           // 8192*768
  unsigned short* Vt  = Kb + (size_t)Mn * Dm;           // 48*64*2048
  unsigned short* Ctx = hbf;                            // reuse (hbf dead after QKV)

  k_cast_hidden<<<dim3(6144), dim3(256), 0, stream>>>(hs, hbf);
  k_cast_w<<<dim3(576, 4), dim3(256), 0, stream>>>(Wq, Wk, Wv, Wo, wbf);
  k_gemm_qkv<<<dim3(6, 64, 3), dim3(256), 0, stream>>>(hbf, wbf, bq, bk, bv, Qb, Kb, Vt);
  k_attn<<<dim3(16, 48), dim3(256), 0, stream>>>(Qb, Kb, Vt, wmix, Ctx);
  k_gemm_out<<<dim3(6, 64), dim3(256), 0, stream>>>(Ctx, wbf + (size_t)3 * Dm * Dm, bo,
                                                    (float*)d_out);
}

// Round 4
// 277.892 us; speedup vs baseline: 1.4481x; 1.0587x over previous
//
#include <hip/hip_runtime.h>

#define DEV __device__ __forceinline__

typedef __attribute__((ext_vector_type(8))) short short8;
typedef __attribute__((ext_vector_type(4))) float f32x4;
typedef __attribute__((ext_vector_type(2))) unsigned int u32x2;
typedef __attribute__((ext_vector_type(4))) unsigned int u32x4;

constexpr int Dm = 768;   // model dim
constexpr int Sn = 2048;  // seq len
constexpr int Bn = 4;     // batch
constexpr int Hn = 12;    // heads
constexpr int Mn = Bn * Sn;  // 8192 rows

// Q is pre-scaled by 0.125*log2(e) so scores come out as s*log2(e):
// p1 = exp2(sacc) = e^s ; p2 = relu(sacc)^2 = (log2e)^2 * relu(s)^2
constexpr float kQScale = 0.18033688011112043f;     // 0.125 * log2(e)
constexpr float kR2Fix  = 0.4804530139182014f;      // 1 / (log2(e))^2

DEV unsigned short f32_to_bf16(float f) {
  unsigned int u = __float_as_uint(f);
  u = (u + 0x7fffu + ((u >> 16) & 1u)) >> 16;
  return (unsigned short)u;
}

// gfx950: pack two fp32 -> bf16x2 dword in ONE VALU op (RNE).
// dst.lo = bf16(lo), dst.hi = bf16(hi)
DEV unsigned cvt_pk_bf16(float lo, float hi) {
  unsigned d;
  asm("v_cvt_pk_bf16_f32 %0, %1, %2" : "=v"(d) : "v"(lo), "v"(hi));
  return d;
}

DEV f32x4 mfma_bf16(short8 a, short8 b, f32x4 c) {
  return __builtin_amdgcn_mfma_f32_16x16x32_bf16(a, b, c, 0, 0, 0);
}

// async global->LDS, 16B per lane; LDS dest = wave-uniform base + lane*16
DEV void gload_lds16(const void* g, void* l) {
  __builtin_amdgcn_global_load_lds(
      (__attribute__((address_space(1))) const unsigned int*)g,
      (__attribute__((address_space(3))) unsigned int*)l, 16, 0, 0);
}

// Transform two 16x16 S^T C-layout tiles (packed as bf16 dwords) into one
// B-operand fragment for mfma_16x16x32 (K=32 keys spanning both tiles).
// xd*: tile keys [0,16) (dword0 = r0,r1 ; dword1 = r2,r3), yd*: keys [16,32).
DEV short8 transpose_to_bfrag(unsigned xd0, unsigned xd1, unsigned yd0, unsigned yd1) {
  u32x2 a0 = __builtin_amdgcn_permlane32_swap(xd0, yd0, false, false);
  u32x2 b0 = __builtin_amdgcn_permlane16_swap(a0[0], a0[1], false, false);
  u32x2 a1 = __builtin_amdgcn_permlane32_swap(xd1, yd1, false, false);
  u32x2 b1 = __builtin_amdgcn_permlane16_swap(a1[0], a1[1], false, false);
  u32x4 f = {b0[0], b1[0], b0[1], b1[1]};
  return __builtin_bit_cast(short8, f);
}

// ---------------- cast kernels ----------------
__global__ __launch_bounds__(256) void k_cast_hidden(const float* __restrict__ src,
                                                     unsigned short* __restrict__ dst) {
  int i = blockIdx.x * 256 + threadIdx.x;
  float4 v = ((const float4*)src)[i];
  ushort4 o;
  o.x = f32_to_bf16(v.x); o.y = f32_to_bf16(v.y);
  o.z = f32_to_bf16(v.z); o.w = f32_to_bf16(v.w);
  ((ushort4*)dst)[i] = o;
}

__global__ __launch_bounds__(256) void k_cast_w(const float* __restrict__ Wq,
                                                const float* __restrict__ Wk,
                                                const float* __restrict__ Wv,
                                                const float* __restrict__ Wo,
                                                unsigned short* __restrict__ wbf) {
  const float* src = (blockIdx.y == 0) ? Wq : (blockIdx.y == 1) ? Wk
                   : (blockIdx.y == 2) ? Wv : Wo;
  unsigned short* dst = wbf + (size_t)blockIdx.y * (Dm * Dm);
  int i = blockIdx.x * 256 + threadIdx.x;
  float4 v = ((const float4*)src)[i];
  ushort4 o;
  o.x = f32_to_bf16(v.x); o.y = f32_to_bf16(v.y);
  o.z = f32_to_bf16(v.z); o.w = f32_to_bf16(v.w);
  ((ushort4*)dst)[i] = o;
}

// ---------------- QKV projection GEMM ----------------
// C[M,N] = A[M,K] * W[N,K]^T + bias ; z=0->Q (pre-scaled), z=1->K, z=2->V transposed
__global__ __launch_bounds__(256, 3) void k_gemm_qkv(
    const unsigned short* __restrict__ Abf, const unsigned short* __restrict__ wbf,
    const float* __restrict__ bq, const float* __restrict__ bk, const float* __restrict__ bv,
    unsigned short* __restrict__ Qb, unsigned short* __restrict__ Kb,
    unsigned short* __restrict__ Vt) {
  __shared__ unsigned short As[128 * 32];
  __shared__ unsigned short Bs[128 * 32];

  const int tid = threadIdx.x;
  const int wave = tid >> 6, lane = tid & 63;
  const int wm = wave >> 1, wn = wave & 1;
  const int quad = lane >> 4, l16 = lane & 15;
  const int bm = blockIdx.y * 128, bn = blockIdx.x * 128;
  const int z = blockIdx.z;

  const unsigned short* W = wbf + (size_t)z * (Dm * Dm);
  const float* bias = (z == 0) ? bq : ((z == 1) ? bk : bv);

  const int sr = lane >> 2;
  const int sc = (lane & 3) * 8;
  const unsigned short* gA0 = Abf + (size_t)(bm + (wave * 2 + 0) * 16 + sr) * Dm + sc;
  const unsigned short* gA1 = Abf + (size_t)(bm + (wave * 2 + 1) * 16 + sr) * Dm + sc;
  const unsigned short* gB0 = W + (size_t)(bn + (wave * 2 + 0) * 16 + sr) * Dm + sc;
  const unsigned short* gB1 = W + (size_t)(bn + (wave * 2 + 1) * 16 + sr) * Dm + sc;
  unsigned short* lA0 = &As[(wave * 2 + 0) * 512];
  unsigned short* lA1 = &As[(wave * 2 + 1) * 512];
  unsigned short* lB0 = &Bs[(wave * 2 + 0) * 512];
  unsigned short* lB1 = &Bs[(wave * 2 + 1) * 512];

  f32x4 acc[4][4];
#pragma unroll
  for (int i = 0; i < 4; ++i)
#pragma unroll
    for (int j = 0; j < 4; ++j)
#pragma unroll
      for (int r = 0; r < 4; ++r) acc[i][j][r] = 0.f;

  for (int kk = 0; kk < Dm; kk += 32) {
    gload_lds16(gA0 + kk, lA0);
    gload_lds16(gA1 + kk, lA1);
    gload_lds16(gB0 + kk, lB0);
    gload_lds16(gB1 + kk, lB1);
    __syncthreads();
    short8 af[4], bf[4];
#pragma unroll
    for (int mi = 0; mi < 4; ++mi)
      af[mi] = *(const short8*)(&As[(wm * 64 + mi * 16 + l16) * 32 + quad * 8]);
#pragma unroll
    for (int ni = 0; ni < 4; ++ni)
      bf[ni] = *(const short8*)(&Bs[(wn * 64 + ni * 16 + l16) * 32 + quad * 8]);
#pragma unroll
    for (int mi = 0; mi < 4; ++mi)
#pragma unroll
      for (int ni = 0; ni < 4; ++ni)
        acc[mi][ni] = mfma_bf16(af[mi], bf[ni], acc[mi][ni]);
    __syncthreads();
  }

#pragma unroll
  for (int ni = 0; ni < 4; ++ni) {
    int n = bn + wn * 64 + ni * 16 + l16;
    float bias_v = bias[n];
    int h = n >> 6, dcol = n & 63;
#pragma unroll
    for (int mi = 0; mi < 4; ++mi) {
#pragma unroll
      for (int r = 0; r < 4; ++r) {
        int m = bm + wm * 64 + mi * 16 + quad * 4 + r;
        float val = acc[mi][ni][r] + bias_v;
        if (z == 0) {
          Qb[(size_t)m * Dm + n] = f32_to_bf16(val * kQScale);
        } else if (z == 1) {
          Kb[(size_t)m * Dm + n] = f32_to_bf16(val);
        } else {
          int b = m >> 11, s = m & 2047;
          Vt[((size_t)((b * Hn + h) * 64 + dcol)) * Sn + s] = f32_to_bf16(val);
        }
      }
    }
  }
}

// ---------------- flash attention (mixed softmax + relu^2) ----------------
// Scores computed TRANSPOSED (S^T = K Q^T) so the PV B-operand is built from
// C-layout fragments with permlane swaps — no P round-trip through LDS.
// Softmax denom computed via ones-row MFMA (A=ones -> D[m][q] = sum_k P[k][q]).
// LDS layouts XOR-swizzled in 16B chunks (conflict-free DMA write + b128 read):
//   Ks[r][c]  (128x64 shorts): off = r*64  + (((c>>3) ^ (r&7))  <<3) + (c&7)
//   Vs[d][s]  (64x128 shorts): off = d*128 + (((s>>3) ^ (d&15)) <<3) + (s&7)
__global__ __launch_bounds__(256, 2) void k_attn(
    const unsigned short* __restrict__ Qb, const unsigned short* __restrict__ Kb,
    const unsigned short* __restrict__ Vt, const float* __restrict__ wmix,
    unsigned short* __restrict__ Ctx) {
  __shared__ unsigned short Ks[128 * 64];
  __shared__ unsigned short Vs[64 * 128];

  const int tid = threadIdx.x;
  const int wave = tid >> 6, lane = tid & 63;
  const int quad = lane >> 4, l16 = lane & 15;
  const int l8 = l16 & 7;
  const int qt = blockIdx.x;   // 16 q-tiles
  const int bh = blockIdx.y;   // 48 = B*H
  const int b = bh / Hn, h = bh % Hn;

  const unsigned short* Qg = Qb + (size_t)(b * Sn + qt * 128) * Dm + h * 64;
  const unsigned short* Kg = Kb + (size_t)(b * Sn) * Dm + h * 64;
  const unsigned short* Vg = Vt + (size_t)bh * 64 * Sn;

  // DMA lane decode: K-style 1KB block = 8 rows x 8 chunks
  const int krr = lane >> 3, kcc = lane & 7;
  const int kchunk = kcc ^ krr;
  // V-style 1KB block = 4 rows x 16 chunks
  const int vrr = lane >> 4, vcc = lane & 15;

  // ---- stage Q tile into Ks via DMA, pull B-frags (q as N dim) ----
#pragma unroll
  for (int i = 0; i < 4; ++i) {
    int t = wave * 4 + i;
    gload_lds16(Qg + (size_t)(t * 8 + krr) * Dm + kchunk * 8, &Ks[t * 512]);
  }
  __syncthreads();
  short8 qf[2][2];
#pragma unroll
  for (int mi = 0; mi < 2; ++mi)
#pragma unroll
    for (int ks = 0; ks < 2; ++ks)
      qf[mi][ks] = *(const short8*)(
          &Ks[(wave * 32 + mi * 16 + l16) * 64 + (((ks * 4 + quad) ^ l8) << 3)]);
  __syncthreads();

  const f32x4 kZero = {0.f, 0.f, 0.f, 0.f};
  short8 ones;
#pragma unroll
  for (int i = 0; i < 8; ++i) ones[i] = (short)0x3F80;  // bf16(1.0)

  // accumulators hold ctx^T: [dh-tile nv][...] rows=dh, cols=q
  f32x4 acc_s[2][4], acc_r2[2][4], lacc[2];
#pragma unroll
  for (int i = 0; i < 2; ++i) {
#pragma unroll
    for (int j = 0; j < 4; ++j)
#pragma unroll
      for (int r = 0; r < 4; ++r) { acc_s[i][j][r] = 0.f; acc_r2[i][j][r] = 0.f; }
#pragma unroll
    for (int r = 0; r < 4; ++r) lacc[i][r] = 0.f;
  }

  for (int kt = 0; kt < 16; ++kt) {
    // stage K tile + V^T tile via DMA
#pragma unroll
    for (int i = 0; i < 4; ++i) {
      int t = wave * 4 + i;
      gload_lds16(Kg + (size_t)(kt * 128 + t * 8 + krr) * Dm + kchunk * 8, &Ks[t * 512]);
    }
#pragma unroll
    for (int i = 0; i < 4; ++i) {
      int t = wave * 4 + i;
      int vrow = t * 4 + vrr;
      int vch = vcc ^ ((4 * i + vrr) & 15);
      gload_lds16(Vg + (size_t)vrow * Sn + kt * 128 + vch * 8, &Vs[t * 512]);
    }
    __syncthreads();

    // process 128 keys as 4 chunks of 32
#pragma unroll
    for (int c = 0; c < 4; ++c) {
      // S^T tiles: rows = keys [c*32, c*32+32), cols = q (32 per wave)
      short8 kf[2][2];
#pragma unroll
      for (int t2 = 0; t2 < 2; ++t2)
#pragma unroll
        for (int ks = 0; ks < 2; ++ks)
          kf[t2][ks] = *(const short8*)(
              &Ks[((c * 2 + t2) * 16 + l16) * 64 + (((ks * 4 + quad) ^ l8) << 3)]);

      f32x4 sacc[2][2];
#pragma unroll
      for (int mi = 0; mi < 2; ++mi)
#pragma unroll
        for (int t2 = 0; t2 < 2; ++t2)
          sacc[mi][t2] = mfma_bf16(kf[t2][1], qf[mi][1],
                                   mfma_bf16(kf[t2][0], qf[mi][0], kZero));

      short8 vf[4];
#pragma unroll
      for (int nv = 0; nv < 4; ++nv)
        vf[nv] = *(const short8*)(
            &Vs[(nv * 16 + l16) * 128 + (((c * 4 + quad) ^ l16) << 3)]);

#pragma unroll
      for (int mi = 0; mi < 2; ++mi) {
        f32x4 s0 = sacc[mi][0], s1 = sacc[mi][1];
        float p1a[4], p1b[4], p2a[4], p2b[4];
#pragma unroll
        for (int r = 0; r < 4; ++r) {
          p1a[r] = __builtin_amdgcn_exp2f(s0[r]);
          p1b[r] = __builtin_amdgcn_exp2f(s1[r]);
          float t0 = fmaxf(s0[r], 0.f), t1 = fmaxf(s1[r], 0.f);
          p2a[r] = t0 * t0;
          p2b[r] = t1 * t1;
        }
        short8 pf1 = transpose_to_bfrag(cvt_pk_bf16(p1a[0], p1a[1]),
                                        cvt_pk_bf16(p1a[2], p1a[3]),
                                        cvt_pk_bf16(p1b[0], p1b[1]),
                                        cvt_pk_bf16(p1b[2], p1b[3]));
        short8 pf2 = transpose_to_bfrag(cvt_pk_bf16(p2a[0], p2a[1]),
                                        cvt_pk_bf16(p2a[2], p2a[3]),
                                        cvt_pk_bf16(p2b[0], p2b[1]),
                                        cvt_pk_bf16(p2b[2], p2b[3]));
#pragma unroll
        for (int nv = 0; nv < 4; ++nv) {
          acc_s[mi][nv] = mfma_bf16(vf[nv], pf1, acc_s[mi][nv]);
          acc_r2[mi][nv] = mfma_bf16(vf[nv], pf2, acc_r2[mi][nv]);
        }
        lacc[mi] = mfma_bf16(ones, pf1, lacc[mi]);  // D[*][q] = sum_k p1
      }
    }
    __syncthreads();
  }

  // epilogue: mix softmax(w_mix), normalize, store bf16 ctx in [B,S,H*DH]
  float w0 = wmix[0], w1 = wmix[1];
  float e0 = __expf(w0), e1 = __expf(w1);
  float mix0 = e0 / (e0 + e1);
  float mix1 = (e1 / (e0 + e1)) * kR2Fix;  // undo (log2e)^2 in relu^2 branch

#pragma unroll
  for (int mi = 0; mi < 2; ++mi) {
    // lacc rows are all identical: lacc[mi][0] = sum_k p1[k][q=l16 of group mi]
    float a0 = mix0 / lacc[mi][0];
    int srow = qt * 128 + wave * 32 + mi * 16 + l16;
#pragma unroll
    for (int nv = 0; nv < 4; ++nv) {
      float v0 = fmaf(acc_s[mi][nv][0], a0, mix1 * acc_r2[mi][nv][0]);
      float v1 = fmaf(acc_s[mi][nv][1], a0, mix1 * acc_r2[mi][nv][1]);
      float v2 = fmaf(acc_s[mi][nv][2], a0, mix1 * acc_r2[mi][nv][2]);
      float v3 = fmaf(acc_s[mi][nv][3], a0, mix1 * acc_r2[mi][nv][3]);
      uint2 o;
      o.x = cvt_pk_bf16(v0, v1);
      o.y = cvt_pk_bf16(v2, v3);
      *(uint2*)(&Ctx[(size_t)(b * Sn + srow) * Dm + h * 64 + nv * 16 + quad * 4]) = o;
    }
  }
}

// ---------------- output projection GEMM (fp32 out) ----------------
__global__ __launch_bounds__(256, 3) void k_gemm_out(
    const unsigned short* __restrict__ Abf, const unsigned short* __restrict__ W,
    const float* __restrict__ bias, float* __restrict__ out) {
  __shared__ unsigned short As[128 * 32];
  __shared__ unsigned short Bs[128 * 32];

  const int tid = threadIdx.x;
  const int wave = tid >> 6, lane = tid & 63;
  const int wm = wave >> 1, wn = wave & 1;
  const int quad = lane >> 4, l16 = lane & 15;
  const int bm = blockIdx.y * 128, bn = blockIdx.x * 128;

  const int sr = lane >> 2;
  const int sc = (lane & 3) * 8;
  const unsigned short* gA0 = Abf + (size_t)(bm + (wave * 2 + 0) * 16 + sr) * Dm + sc;
  const unsigned short* gA1 = Abf + (size_t)(bm + (wave * 2 + 1) * 16 + sr) * Dm + sc;
  const unsigned short* gB0 = W + (size_t)(bn + (wave * 2 + 0) * 16 + sr) * Dm + sc;
  const unsigned short* gB1 = W + (size_t)(bn + (wave * 2 + 1) * 16 + sr) * Dm + sc;
  unsigned short* lA0 = &As[(wave * 2 + 0) * 512];
  unsigned short* lA1 = &As[(wave * 2 + 1) * 512];
  unsigned short* lB0 = &Bs[(wave * 2 + 0) * 512];
  unsigned short* lB1 = &Bs[(wave * 2 + 1) * 512];

  f32x4 acc[4][4];
#pragma unroll
  for (int i = 0; i < 4; ++i)
#pragma unroll
    for (int j = 0; j < 4; ++j)
#pragma unroll
      for (int r = 0; r < 4; ++r) acc[i][j][r] = 0.f;

  for (int kk = 0; kk < Dm; kk += 32) {
    gload_lds16(gA0 + kk, lA0);
    gload_lds16(gA1 + kk, lA1);
    gload_lds16(gB0 + kk, lB0);
    gload_lds16(gB1 + kk, lB1);
    __syncthreads();
    short8 af[4], bf[4];
#pragma unroll
    for (int mi = 0; mi < 4; ++mi)
      af[mi] = *(const short8*)(&As[(wm * 64 + mi * 16 + l16) * 32 + quad * 8]);
#pragma unroll
    for (int ni = 0; ni < 4; ++ni)
      bf[ni] = *(const short8*)(&Bs[(wn * 64 + ni * 16 + l16) * 32 + quad * 8]);
#pragma unroll
    for (int mi = 0; mi < 4; ++mi)
#pragma unroll
      for (int ni = 0; ni < 4; ++ni)
        acc[mi][ni] = mfma_bf16(af[mi], bf[ni], acc[mi][ni]);
    __syncthreads();
  }

#pragma unroll
  for (int ni = 0; ni < 4; ++ni) {
    int n = bn + wn * 64 + ni * 16 + l16;
    float bias_v = bias[n];
#pragma unroll
    for (int mi = 0; mi < 4; ++mi) {
#pragma unroll
      for (int r = 0; r < 4; ++r) {
        int m = bm + wm * 64 + mi * 16 + quad * 4 + r;
        out[(size_t)m * Dm + n] = acc[mi][ni][r] + bias_v;
      }
    }
  }
}

extern "C" void kernel_launch(void* const* d_in, const int* in_sizes, int n_in,
                              void* d_out, int out_size, void* d_ws, size_t ws_size,
                              hipStream_t stream) {
  const float* hs = (const float*)d_in[0];
  const float* Wq = (const float*)d_in[1];
  const float* bq = (const float*)d_in[2];
  const float* Wk = (const float*)d_in[3];
  const float* bk = (const float*)d_in[4];
  const float* Wv = (const float*)d_in[5];
  const float* bv = (const float*)d_in[6];
  const float* Wo = (const float*)d_in[7];
  const float* bo = (const float*)d_in[8];
  const float* wmix = (const float*)d_in[9];

  unsigned short* hbf = (unsigned short*)d_ws;          // 8192*768
  unsigned short* wbf = hbf + (size_t)Mn * Dm;          // 4*768*768
  unsigned short* Qb  = wbf + (size_t)4 * Dm * Dm;      // 8192*768
  unsigned short* Kb  = Qb + (size_t)Mn * Dm;           // 8192*768
  unsigned short* Vt  = Kb + (size_t)Mn * Dm;           // 48*64*2048
  unsigned short* Ctx = hbf;                            // reuse (hbf dead after QKV)

  k_cast_hidden<<<dim3(6144), dim3(256), 0, stream>>>(hs, hbf);
  k_cast_w<<<dim3(576, 4), dim3(256), 0, stream>>>(Wq, Wk, Wv, Wo, wbf);
  k_gemm_qkv<<<dim3(6, 64, 3), dim3(256), 0, stream>>>(hbf, wbf, bq, bk, bv, Qb, Kb, Vt);
  k_attn<<<dim3(16, 48), dim3(256), 0, stream>>>(Qb, Kb, Vt, wmix, Ctx);
  k_gemm_out<<<dim3(6, 64), dim3(256), 0, stream>>>(Ctx, wbf + (size_t)3 * Dm * Dm, bo,
                                                    (float*)d_out);
}

// Round 5
// 260.150 us; speedup vs baseline: 1.5469x; 1.0682x over previous
//
#include <hip/hip_runtime.h>

#define DEV __device__ __forceinline__

typedef __attribute__((ext_vector_type(8))) short short8;
typedef __attribute__((ext_vector_type(4))) float f32x4;
typedef __attribute__((ext_vector_type(2))) unsigned int u32x2;
typedef __attribute__((ext_vector_type(4))) unsigned int u32x4;

constexpr int Dm = 768;   // model dim
constexpr int Sn = 2048;  // seq len
constexpr int Bn = 4;     // batch
constexpr int Hn = 12;    // heads
constexpr int Mn = Bn * Sn;  // 8192 rows

// Q is pre-scaled by 0.125*log2(e) so scores come out as s*log2(e):
// p1 = exp2(sacc) = e^s ; p2 = relu(sacc)^2 = (log2e)^2 * relu(s)^2
constexpr float kQScale = 0.18033688011112043f;     // 0.125 * log2(e)
constexpr float kR2Fix  = 0.4804530139182014f;      // 1 / (log2(e))^2

DEV unsigned short f32_to_bf16(float f) {
  unsigned int u = __float_as_uint(f);
  u = (u + 0x7fffu + ((u >> 16) & 1u)) >> 16;
  return (unsigned short)u;
}

// gfx950: pack two fp32 -> bf16x2 dword in ONE VALU op (RNE).
// dst.lo = bf16(lo), dst.hi = bf16(hi)
DEV unsigned cvt_pk_bf16(float lo, float hi) {
  unsigned d;
  asm("v_cvt_pk_bf16_f32 %0, %1, %2" : "=v"(d) : "v"(lo), "v"(hi));
  return d;
}

DEV f32x4 mfma_bf16(short8 a, short8 b, f32x4 c) {
  return __builtin_amdgcn_mfma_f32_16x16x32_bf16(a, b, c, 0, 0, 0);
}

// async global->LDS, 16B per lane; LDS dest = wave-uniform base + lane*16
DEV void gload_lds16(const void* g, void* l) {
  __builtin_amdgcn_global_load_lds(
      (__attribute__((address_space(1))) const unsigned int*)g,
      (__attribute__((address_space(3))) unsigned int*)l, 16, 0, 0);
}

// Transform two 16x16 S^T C-layout tiles (packed as bf16 dwords) into one
// B-operand fragment for mfma_16x16x32 (K=32 keys spanning both tiles).
DEV short8 transpose_to_bfrag(unsigned xd0, unsigned xd1, unsigned yd0, unsigned yd1) {
  u32x2 a0 = __builtin_amdgcn_permlane32_swap(xd0, yd0, false, false);
  u32x2 b0 = __builtin_amdgcn_permlane16_swap(a0[0], a0[1], false, false);
  u32x2 a1 = __builtin_amdgcn_permlane32_swap(xd1, yd1, false, false);
  u32x2 b1 = __builtin_amdgcn_permlane16_swap(a1[0], a1[1], false, false);
  u32x4 f = {b0[0], b1[0], b0[1], b1[1]};
  return __builtin_bit_cast(short8, f);
}

// ---------------- cast kernels ----------------
__global__ __launch_bounds__(256) void k_cast_hidden(const float* __restrict__ src,
                                                     unsigned short* __restrict__ dst) {
  int i = blockIdx.x * 256 + threadIdx.x;
  float4 v = ((const float4*)src)[i];
  ushort4 o;
  o.x = f32_to_bf16(v.x); o.y = f32_to_bf16(v.y);
  o.z = f32_to_bf16(v.z); o.w = f32_to_bf16(v.w);
  ((ushort4*)dst)[i] = o;
}

__global__ __launch_bounds__(256) void k_cast_w(const float* __restrict__ Wq,
                                                const float* __restrict__ Wk,
                                                const float* __restrict__ Wv,
                                                const float* __restrict__ Wo,
                                                unsigned short* __restrict__ wbf) {
  const float* src = (blockIdx.y == 0) ? Wq : (blockIdx.y == 1) ? Wk
                   : (blockIdx.y == 2) ? Wv : Wo;
  unsigned short* dst = wbf + (size_t)blockIdx.y * (Dm * Dm);
  int i = blockIdx.x * 256 + threadIdx.x;
  float4 v = ((const float4*)src)[i];
  ushort4 o;
  o.x = f32_to_bf16(v.x); o.y = f32_to_bf16(v.y);
  o.z = f32_to_bf16(v.z); o.w = f32_to_bf16(v.w);
  ((ushort4*)dst)[i] = o;
}

// ---------------- QKV projection GEMM ----------------
// C[M,N] = A[M,K] * W[N,K]^T + bias ; z=0->Q (pre-scaled), z=1->K,
// z=2->V transposed [B,H,DH,S] via LDS-transpose epilogue (coalesced stores).
__global__ __launch_bounds__(256, 3) void k_gemm_qkv(
    const unsigned short* __restrict__ Abf, const unsigned short* __restrict__ wbf,
    const float* __restrict__ bq, const float* __restrict__ bk, const float* __restrict__ bv,
    unsigned short* __restrict__ Qb, unsigned short* __restrict__ Kb,
    unsigned short* __restrict__ Vt) {
  // union: staging As (4096) + Bs (4096) shorts; epilogue reuses as 128x136 tile
  __shared__ unsigned short Sh[128 * 136];
  unsigned short* As = Sh;
  unsigned short* Bs = Sh + 4096;

  const int tid = threadIdx.x;
  const int wave = tid >> 6, lane = tid & 63;
  const int wm = wave >> 1, wn = wave & 1;
  const int quad = lane >> 4, l16 = lane & 15;
  const int bm = blockIdx.y * 128, bn = blockIdx.x * 128;
  const int z = blockIdx.z;

  const unsigned short* W = wbf + (size_t)z * (Dm * Dm);
  const float* bias = (z == 0) ? bq : ((z == 1) ? bk : bv);

  const int sr = lane >> 2;
  const int sc = (lane & 3) * 8;
  const unsigned short* gA0 = Abf + (size_t)(bm + (wave * 2 + 0) * 16 + sr) * Dm + sc;
  const unsigned short* gA1 = Abf + (size_t)(bm + (wave * 2 + 1) * 16 + sr) * Dm + sc;
  const unsigned short* gB0 = W + (size_t)(bn + (wave * 2 + 0) * 16 + sr) * Dm + sc;
  const unsigned short* gB1 = W + (size_t)(bn + (wave * 2 + 1) * 16 + sr) * Dm + sc;
  unsigned short* lA0 = &As[(wave * 2 + 0) * 512];
  unsigned short* lA1 = &As[(wave * 2 + 1) * 512];
  unsigned short* lB0 = &Bs[(wave * 2 + 0) * 512];
  unsigned short* lB1 = &Bs[(wave * 2 + 1) * 512];

  f32x4 acc[4][4];
#pragma unroll
  for (int i = 0; i < 4; ++i)
#pragma unroll
    for (int j = 0; j < 4; ++j)
#pragma unroll
      for (int r = 0; r < 4; ++r) acc[i][j][r] = 0.f;

  for (int kk = 0; kk < Dm; kk += 32) {
    gload_lds16(gA0 + kk, lA0);
    gload_lds16(gA1 + kk, lA1);
    gload_lds16(gB0 + kk, lB0);
    gload_lds16(gB1 + kk, lB1);
    __syncthreads();
    short8 af[4], bf[4];
#pragma unroll
    for (int mi = 0; mi < 4; ++mi)
      af[mi] = *(const short8*)(&As[(wm * 64 + mi * 16 + l16) * 32 + quad * 8]);
#pragma unroll
    for (int ni = 0; ni < 4; ++ni)
      bf[ni] = *(const short8*)(&Bs[(wn * 64 + ni * 16 + l16) * 32 + quad * 8]);
#pragma unroll
    for (int mi = 0; mi < 4; ++mi)
#pragma unroll
      for (int ni = 0; ni < 4; ++ni)
        acc[mi][ni] = mfma_bf16(af[mi], bf[ni], acc[mi][ni]);
    __syncthreads();
  }

  if (z != 2) {
#pragma unroll
    for (int ni = 0; ni < 4; ++ni) {
      int n = bn + wn * 64 + ni * 16 + l16;
      float bias_v = bias[n];
#pragma unroll
      for (int mi = 0; mi < 4; ++mi) {
#pragma unroll
        for (int r = 0; r < 4; ++r) {
          int m = bm + wm * 64 + mi * 16 + quad * 4 + r;
          float val = acc[mi][ni][r] + bias_v;
          if (z == 0)
            Qb[(size_t)m * Dm + n] = f32_to_bf16(val * kQScale);
          else
            Kb[(size_t)m * Dm + n] = f32_to_bf16(val);
        }
      }
    }
  } else {
    // V: write acc TRANSPOSED into LDS tile [n_local][m_local], stride 136,
    // then store coalesced 256B rows of V^T [B,H,DH,S].
#pragma unroll
    for (int ni = 0; ni < 4; ++ni) {
      int nl = wn * 64 + ni * 16 + l16;
      float bias_v = bias[bn + nl];
#pragma unroll
      for (int mi = 0; mi < 4; ++mi) {
#pragma unroll
        for (int r = 0; r < 4; ++r) {
          int ml = wm * 64 + mi * 16 + quad * 4 + r;
          Sh[nl * 136 + ml] = f32_to_bf16(acc[mi][ni][r] + bias_v);
        }
      }
    }
    __syncthreads();
    const int bb = bm >> 11;        // batch (bm aligned to 128, 2048 per batch)
    const int s0 = bm & 2047;       // seq offset
    const int j = tid >> 4;         // 0..15 row-group
    const int cch = tid & 15;       // 16B chunk within row
#pragma unroll
    for (int pass = 0; pass < 8; ++pass) {
      int row = pass * 16 + j;      // n_local 0..127
      int n = bn + row;
      int h2 = n >> 6, dcol = n & 63;
      uint4 v = *(const uint4*)(&Sh[row * 136 + cch * 8]);
      *(uint4*)(&Vt[((size_t)((bb * Hn + h2) * 64 + dcol)) * Sn + s0 + cch * 8]) = v;
    }
  }
}

// ---------------- flash attention (mixed softmax + relu^2) ----------------
// Scores computed TRANSPOSED (S^T = K Q^T) so the PV B-operand is built from
// C-layout fragments with permlane swaps — no P round-trip through LDS.
// Softmax denom via ones-row MFMA. XOR-swizzled LDS (conflict-free DMA+b128).
__global__ __launch_bounds__(256, 2) void k_attn(
    const unsigned short* __restrict__ Qb, const unsigned short* __restrict__ Kb,
    const unsigned short* __restrict__ Vt, const float* __restrict__ wmix,
    unsigned short* __restrict__ Ctx) {
  __shared__ unsigned short Ks[128 * 64];
  __shared__ unsigned short Vs[64 * 128];

  const int tid = threadIdx.x;
  const int wave = tid >> 6, lane = tid & 63;
  const int quad = lane >> 4, l16 = lane & 15;
  const int l8 = l16 & 7;
  const int qt = blockIdx.x;   // 16 q-tiles
  const int bh = blockIdx.y;   // 48 = B*H
  const int b = bh / Hn, h = bh % Hn;

  const unsigned short* Qg = Qb + (size_t)(b * Sn + qt * 128) * Dm + h * 64;
  const unsigned short* Kg = Kb + (size_t)(b * Sn) * Dm + h * 64;
  const unsigned short* Vg = Vt + (size_t)bh * 64 * Sn;

  const int krr = lane >> 3, kcc = lane & 7;
  const int kchunk = kcc ^ krr;
  const int vrr = lane >> 4, vcc = lane & 15;

#pragma unroll
  for (int i = 0; i < 4; ++i) {
    int t = wave * 4 + i;
    gload_lds16(Qg + (size_t)(t * 8 + krr) * Dm + kchunk * 8, &Ks[t * 512]);
  }
  __syncthreads();
  short8 qf[2][2];
#pragma unroll
  for (int mi = 0; mi < 2; ++mi)
#pragma unroll
    for (int ks = 0; ks < 2; ++ks)
      qf[mi][ks] = *(const short8*)(
          &Ks[(wave * 32 + mi * 16 + l16) * 64 + (((ks * 4 + quad) ^ l8) << 3)]);
  __syncthreads();

  const f32x4 kZero = {0.f, 0.f, 0.f, 0.f};
  short8 ones;
#pragma unroll
  for (int i = 0; i < 8; ++i) ones[i] = (short)0x3F80;  // bf16(1.0)

  f32x4 acc_s[2][4], acc_r2[2][4], lacc[2];
#pragma unroll
  for (int i = 0; i < 2; ++i) {
#pragma unroll
    for (int j = 0; j < 4; ++j)
#pragma unroll
      for (int r = 0; r < 4; ++r) { acc_s[i][j][r] = 0.f; acc_r2[i][j][r] = 0.f; }
#pragma unroll
    for (int r = 0; r < 4; ++r) lacc[i][r] = 0.f;
  }

  for (int kt = 0; kt < 16; ++kt) {
#pragma unroll
    for (int i = 0; i < 4; ++i) {
      int t = wave * 4 + i;
      gload_lds16(Kg + (size_t)(kt * 128 + t * 8 + krr) * Dm + kchunk * 8, &Ks[t * 512]);
    }
#pragma unroll
    for (int i = 0; i < 4; ++i) {
      int t = wave * 4 + i;
      int vrow = t * 4 + vrr;
      int vch = vcc ^ ((4 * i + vrr) & 15);
      gload_lds16(Vg + (size_t)vrow * Sn + kt * 128 + vch * 8, &Vs[t * 512]);
    }
    __syncthreads();

#pragma unroll
    for (int c = 0; c < 4; ++c) {
      short8 kf[2][2];
#pragma unroll
      for (int t2 = 0; t2 < 2; ++t2)
#pragma unroll
        for (int ks = 0; ks < 2; ++ks)
          kf[t2][ks] = *(const short8*)(
              &Ks[((c * 2 + t2) * 16 + l16) * 64 + (((ks * 4 + quad) ^ l8) << 3)]);

      f32x4 sacc[2][2];
#pragma unroll
      for (int mi = 0; mi < 2; ++mi)
#pragma unroll
        for (int t2 = 0; t2 < 2; ++t2)
          sacc[mi][t2] = mfma_bf16(kf[t2][1], qf[mi][1],
                                   mfma_bf16(kf[t2][0], qf[mi][0], kZero));

      short8 vf[4];
#pragma unroll
      for (int nv = 0; nv < 4; ++nv)
        vf[nv] = *(const short8*)(
            &Vs[(nv * 16 + l16) * 128 + (((c * 4 + quad) ^ l16) << 3)]);

#pragma unroll
      for (int mi = 0; mi < 2; ++mi) {
        f32x4 s0 = sacc[mi][0], s1 = sacc[mi][1];
        float p1a[4], p1b[4], p2a[4], p2b[4];
#pragma unroll
        for (int r = 0; r < 4; ++r) {
          p1a[r] = __builtin_amdgcn_exp2f(s0[r]);
          p1b[r] = __builtin_amdgcn_exp2f(s1[r]);
          float t0 = fmaxf(s0[r], 0.f), t1 = fmaxf(s1[r], 0.f);
          p2a[r] = t0 * t0;
          p2b[r] = t1 * t1;
        }
        short8 pf1 = transpose_to_bfrag(cvt_pk_bf16(p1a[0], p1a[1]),
                                        cvt_pk_bf16(p1a[2], p1a[3]),
                                        cvt_pk_bf16(p1b[0], p1b[1]),
                                        cvt_pk_bf16(p1b[2], p1b[3]));
        short8 pf2 = transpose_to_bfrag(cvt_pk_bf16(p2a[0], p2a[1]),
                                        cvt_pk_bf16(p2a[2], p2a[3]),
                                        cvt_pk_bf16(p2b[0], p2b[1]),
                                        cvt_pk_bf16(p2b[2], p2b[3]));
#pragma unroll
        for (int nv = 0; nv < 4; ++nv) {
          acc_s[mi][nv] = mfma_bf16(vf[nv], pf1, acc_s[mi][nv]);
          acc_r2[mi][nv] = mfma_bf16(vf[nv], pf2, acc_r2[mi][nv]);
        }
        lacc[mi] = mfma_bf16(ones, pf1, lacc[mi]);  // D[*][q] = sum_k p1
      }
    }
    __syncthreads();
  }

  float w0 = wmix[0], w1 = wmix[1];
  float e0 = __expf(w0), e1 = __expf(w1);
  float mix0 = e0 / (e0 + e1);
  float mix1 = (e1 / (e0 + e1)) * kR2Fix;  // undo (log2e)^2 in relu^2 branch

#pragma unroll
  for (int mi = 0; mi < 2; ++mi) {
    float a0 = mix0 / lacc[mi][0];
    int srow = qt * 128 + wave * 32 + mi * 16 + l16;
#pragma unroll
    for (int nv = 0; nv < 4; ++nv) {
      float v0 = fmaf(acc_s[mi][nv][0], a0, mix1 * acc_r2[mi][nv][0]);
      float v1 = fmaf(acc_s[mi][nv][1], a0, mix1 * acc_r2[mi][nv][1]);
      float v2 = fmaf(acc_s[mi][nv][2], a0, mix1 * acc_r2[mi][nv][2]);
      float v3 = fmaf(acc_s[mi][nv][3], a0, mix1 * acc_r2[mi][nv][3]);
      uint2 o;
      o.x = cvt_pk_bf16(v0, v1);
      o.y = cvt_pk_bf16(v2, v3);
      *(uint2*)(&Ctx[(size_t)(b * Sn + srow) * Dm + h * 64 + nv * 16 + quad * 4]) = o;
    }
  }
}

// ---------------- output projection GEMM (fp32 out) ----------------
__global__ __launch_bounds__(256, 3) void k_gemm_out(
    const unsigned short* __restrict__ Abf, const unsigned short* __restrict__ W,
    const float* __restrict__ bias, float* __restrict__ out) {
  __shared__ unsigned short As[128 * 32];
  __shared__ unsigned short Bs[128 * 32];

  const int tid = threadIdx.x;
  const int wave = tid >> 6, lane = tid & 63;
  const int wm = wave >> 1, wn = wave & 1;
  const int quad = lane >> 4, l16 = lane & 15;
  const int bm = blockIdx.y * 128, bn = blockIdx.x * 128;

  const int sr = lane >> 2;
  const int sc = (lane & 3) * 8;
  const unsigned short* gA0 = Abf + (size_t)(bm + (wave * 2 + 0) * 16 + sr) * Dm + sc;
  const unsigned short* gA1 = Abf + (size_t)(bm + (wave * 2 + 1) * 16 + sr) * Dm + sc;
  const unsigned short* gB0 = W + (size_t)(bn + (wave * 2 + 0) * 16 + sr) * Dm + sc;
  const unsigned short* gB1 = W + (size_t)(bn + (wave * 2 + 1) * 16 + sr) * Dm + sc;
  unsigned short* lA0 = &As[(wave * 2 + 0) * 512];
  unsigned short* lA1 = &As[(wave * 2 + 1) * 512];
  unsigned short* lB0 = &Bs[(wave * 2 + 0) * 512];
  unsigned short* lB1 = &Bs[(wave * 2 + 1) * 512];

  f32x4 acc[4][4];
#pragma unroll
  for (int i = 0; i < 4; ++i)
#pragma unroll
    for (int j = 0; j < 4; ++j)
#pragma unroll
      for (int r = 0; r < 4; ++r) acc[i][j][r] = 0.f;

  for (int kk = 0; kk < Dm; kk += 32) {
    gload_lds16(gA0 + kk, lA0);
    gload_lds16(gA1 + kk, lA1);
    gload_lds16(gB0 + kk, lB0);
    gload_lds16(gB1 + kk, lB1);
    __syncthreads();
    short8 af[4], bf[4];
#pragma unroll
    for (int mi = 0; mi < 4; ++mi)
      af[mi] = *(const short8*)(&As[(wm * 64 + mi * 16 + l16) * 32 + quad * 8]);
#pragma unroll
    for (int ni = 0; ni < 4; ++ni)
      bf[ni] = *(const short8*)(&Bs[(wn * 64 + ni * 16 + l16) * 32 + quad * 8]);
#pragma unroll
    for (int mi = 0; mi < 4; ++mi)
#pragma unroll
      for (int ni = 0; ni < 4; ++ni)
        acc[mi][ni] = mfma_bf16(af[mi], bf[ni], acc[mi][ni]);
    __syncthreads();
  }

#pragma unroll
  for (int ni = 0; ni < 4; ++ni) {
    int n = bn + wn * 64 + ni * 16 + l16;
    float bias_v = bias[n];
#pragma unroll
    for (int mi = 0; mi < 4; ++mi) {
#pragma unroll
      for (int r = 0; r < 4; ++r) {
        int m = bm + wm * 64 + mi * 16 + quad * 4 + r;
        out[(size_t)m * Dm + n] = acc[mi][ni][r] + bias_v;
      }
    }
  }
}

extern "C" void kernel_launch(void* const* d_in, const int* in_sizes, int n_in,
                              void* d_out, int out_size, void* d_ws, size_t ws_size,
                              hipStream_t stream) {
  const float* hs = (const float*)d_in[0];
  const float* Wq = (const float*)d_in[1];
  const float* bq = (const float*)d_in[2];
  const float* Wk = (const float*)d_in[3];
  const float* bk = (const float*)d_in[4];
  const float* Wv = (const float*)d_in[5];
  const float* bv = (const float*)d_in[6];
  const float* Wo = (const float*)d_in[7];
  const float* bo = (const float*)d_in[8];
  const float* wmix = (const float*)d_in[9];

  unsigned short* hbf = (unsigned short*)d_ws;          // 8192*768
  unsigned short* wbf = hbf + (size_t)Mn * Dm;          // 4*768*768
  unsigned short* Qb  = wbf + (size_t)4 * Dm * Dm;      // 8192*768
  unsigned short* Kb  = Qb + (size_t)Mn * Dm;           // 8192*768
  unsigned short* Vt  = Kb + (size_t)Mn * Dm;           // 48*64*2048
  unsigned short* Ctx = hbf;                            // reuse (hbf dead after QKV)

  k_cast_hidden<<<dim3(6144), dim3(256), 0, stream>>>(hs, hbf);
  k_cast_w<<<dim3(576, 4), dim3(256), 0, stream>>>(Wq, Wk, Wv, Wo, wbf);
  k_gemm_qkv<<<dim3(6, 64, 3), dim3(256), 0, stream>>>(hbf, wbf, bq, bk, bv, Qb, Kb, Vt);
  k_attn<<<dim3(16, 48), dim3(256), 0, stream>>>(Qb, Kb, Vt, wmix, Ctx);
  k_gemm_out<<<dim3(6, 64), dim3(256), 0, stream>>>(Ctx, wbf + (size_t)3 * Dm * Dm, bo,
                                                    (float*)d_out);
}

// Round 6
// 259.335 us; speedup vs baseline: 1.5517x; 1.0031x over previous
//
#include <hip/hip_runtime.h>

#define DEV __device__ __forceinline__

typedef __attribute__((ext_vector_type(8))) short short8;
typedef __attribute__((ext_vector_type(4))) float f32x4;
typedef __attribute__((ext_vector_type(2))) unsigned int u32x2;
typedef __attribute__((ext_vector_type(4))) unsigned int u32x4;

constexpr int Dm = 768;   // model dim
constexpr int Sn = 2048;  // seq len
constexpr int Bn = 4;     // batch
constexpr int Hn = 12;    // heads
constexpr int Mn = Bn * Sn;  // 8192 rows

// Q is pre-scaled by 0.125*log2(e) so scores come out as s*log2(e):
// p1 = exp2(sacc) = e^s ; p2 = relu(sacc)^2 = (log2e)^2 * relu(s)^2
constexpr float kQScale = 0.18033688011112043f;     // 0.125 * log2(e)
constexpr float kR2Fix  = 0.4804530139182014f;      // 1 / (log2(e))^2

DEV unsigned short f32_to_bf16(float f) {
  unsigned int u = __float_as_uint(f);
  u = (u + 0x7fffu + ((u >> 16) & 1u)) >> 16;
  return (unsigned short)u;
}

// gfx950: pack two fp32 -> bf16x2 dword in ONE VALU op (RNE).
DEV unsigned cvt_pk_bf16(float lo, float hi) {
  unsigned d;
  asm("v_cvt_pk_bf16_f32 %0, %1, %2" : "=v"(d) : "v"(lo), "v"(hi));
  return d;
}

DEV f32x4 mfma_bf16(short8 a, short8 b, f32x4 c) {
  return __builtin_amdgcn_mfma_f32_16x16x32_bf16(a, b, c, 0, 0, 0);
}

// async global->LDS, 16B per lane; LDS dest = wave-uniform base + lane*16
DEV void gload_lds16(const void* g, void* l) {
  __builtin_amdgcn_global_load_lds(
      (__attribute__((address_space(1))) const unsigned int*)g,
      (__attribute__((address_space(3))) unsigned int*)l, 16, 0, 0);
}

// Transform two 16x16 S^T C-layout tiles (packed as bf16 dwords) into one
// B-operand fragment for mfma_16x16x32 (K=32 keys spanning both tiles).
DEV short8 transpose_to_bfrag(unsigned xd0, unsigned xd1, unsigned yd0, unsigned yd1) {
  u32x2 a0 = __builtin_amdgcn_permlane32_swap(xd0, yd0, false, false);
  u32x2 b0 = __builtin_amdgcn_permlane16_swap(a0[0], a0[1], false, false);
  u32x2 a1 = __builtin_amdgcn_permlane32_swap(xd1, yd1, false, false);
  u32x2 b1 = __builtin_amdgcn_permlane16_swap(a1[0], a1[1], false, false);
  u32x4 f = {b0[0], b1[0], b0[1], b1[1]};
  return __builtin_bit_cast(short8, f);
}

// ---------------- cast kernels ----------------
__global__ __launch_bounds__(256) void k_cast_hidden(const float* __restrict__ src,
                                                     unsigned short* __restrict__ dst) {
  int i = blockIdx.x * 256 + threadIdx.x;
  float4 v = ((const float4*)src)[i];
  ushort4 o;
  o.x = f32_to_bf16(v.x); o.y = f32_to_bf16(v.y);
  o.z = f32_to_bf16(v.z); o.w = f32_to_bf16(v.w);
  ((ushort4*)dst)[i] = o;
}

__global__ __launch_bounds__(256) void k_cast_w(const float* __restrict__ Wq,
                                                const float* __restrict__ Wk,
                                                const float* __restrict__ Wv,
                                                const float* __restrict__ Wo,
                                                unsigned short* __restrict__ wbf) {
  const float* src = (blockIdx.y == 0) ? Wq : (blockIdx.y == 1) ? Wk
                   : (blockIdx.y == 2) ? Wv : Wo;
  unsigned short* dst = wbf + (size_t)blockIdx.y * (Dm * Dm);
  int i = blockIdx.x * 256 + threadIdx.x;
  float4 v = ((const float4*)src)[i];
  ushort4 o;
  o.x = f32_to_bf16(v.x); o.y = f32_to_bf16(v.y);
  o.z = f32_to_bf16(v.z); o.w = f32_to_bf16(v.w);
  ((ushort4*)dst)[i] = o;
}

// ---------------- merged QKV projection GEMM ----------------
// One GEMM over stacked W' = [Wq;Wk;Wv] (N'=2304). Tile 128(M) x 192(N),
// grid 12x64 = 768 blocks = exactly one round at 3 blocks/CU.
// Block-uniform segment: bx 0-3 -> Q (pre-scaled), 4-7 -> K, 8-11 -> V
// (V stored transposed [B,H,DH,S] via two-pass 96-row LDS transpose).
__global__ __launch_bounds__(256, 3) void k_gemm_qkv(
    const unsigned short* __restrict__ Abf, const unsigned short* __restrict__ wbf,
    const float* __restrict__ bq, const float* __restrict__ bk, const float* __restrict__ bv,
    unsigned short* __restrict__ Qb, unsigned short* __restrict__ Kb,
    unsigned short* __restrict__ Vt) {
  // union: staging As[128x32]=4096 + Bs[192x32]=6144 shorts (20.5 KB)
  //        | V-transpose tile [96][136] = 13056 shorts (26 KB)
  __shared__ unsigned short Sh[96 * 136];
  unsigned short* As = Sh;
  unsigned short* Bs = Sh + 4096;

  const int tid = threadIdx.x;
  const int wave = tid >> 6, lane = tid & 63;
  const int wm = wave >> 1, wn = wave & 1;
  const int quad = lane >> 4, l16 = lane & 15;
  const int bm = blockIdx.y * 128, bn = blockIdx.x * 192;
  const int seg = blockIdx.x >> 2;            // 0=Q 1=K 2=V
  const int nloc0 = (blockIdx.x & 3) * 192;   // column offset within 768

  const int sr = lane >> 2;
  const int sc = (lane & 3) * 8;
  const unsigned short* gA0 = Abf + (size_t)(bm + (wave * 2 + 0) * 16 + sr) * Dm + sc;
  const unsigned short* gA1 = Abf + (size_t)(bm + (wave * 2 + 1) * 16 + sr) * Dm + sc;
  const unsigned short* gB0 = wbf + (size_t)(bn + (wave * 3 + 0) * 16 + sr) * Dm + sc;
  const unsigned short* gB1 = wbf + (size_t)(bn + (wave * 3 + 1) * 16 + sr) * Dm + sc;
  const unsigned short* gB2 = wbf + (size_t)(bn + (wave * 3 + 2) * 16 + sr) * Dm + sc;
  unsigned short* lA0 = &As[(wave * 2 + 0) * 512];
  unsigned short* lA1 = &As[(wave * 2 + 1) * 512];
  unsigned short* lB0 = &Bs[(wave * 3 + 0) * 512];
  unsigned short* lB1 = &Bs[(wave * 3 + 1) * 512];
  unsigned short* lB2 = &Bs[(wave * 3 + 2) * 512];

  f32x4 acc[4][6];
#pragma unroll
  for (int i = 0; i < 4; ++i)
#pragma unroll
    for (int j = 0; j < 6; ++j)
#pragma unroll
      for (int r = 0; r < 4; ++r) acc[i][j][r] = 0.f;

  for (int kk = 0; kk < Dm; kk += 32) {
    gload_lds16(gA0 + kk, lA0);
    gload_lds16(gA1 + kk, lA1);
    gload_lds16(gB0 + kk, lB0);
    gload_lds16(gB1 + kk, lB1);
    gload_lds16(gB2 + kk, lB2);
    __syncthreads();
    short8 af[4], bf[6];
#pragma unroll
    for (int mi = 0; mi < 4; ++mi)
      af[mi] = *(const short8*)(&As[(wm * 64 + mi * 16 + l16) * 32 + quad * 8]);
#pragma unroll
    for (int ni = 0; ni < 6; ++ni)
      bf[ni] = *(const short8*)(&Bs[(wn * 96 + ni * 16 + l16) * 32 + quad * 8]);
#pragma unroll
    for (int mi = 0; mi < 4; ++mi)
#pragma unroll
      for (int ni = 0; ni < 6; ++ni)
        acc[mi][ni] = mfma_bf16(af[mi], bf[ni], acc[mi][ni]);
    __syncthreads();
  }

  if (seg != 2) {
    const float* bias = (seg == 0) ? bq : bk;
    unsigned short* Out = (seg == 0) ? Qb : Kb;
    const float scale = (seg == 0) ? kQScale : 1.0f;
#pragma unroll
    for (int ni = 0; ni < 6; ++ni) {
      int n = nloc0 + wn * 96 + ni * 16 + l16;
      float bias_v = bias[n];
#pragma unroll
      for (int mi = 0; mi < 4; ++mi) {
#pragma unroll
        for (int r = 0; r < 4; ++r) {
          int m = bm + wm * 64 + mi * 16 + quad * 4 + r;
          Out[(size_t)m * Dm + n] = f32_to_bf16((acc[mi][ni][r] + bias_v) * scale);
        }
      }
    }
  } else {
    // V: two-pass LDS transpose, then coalesced 256B-row stores of V^T.
    const int bb = bm >> 11;       // batch
    const int s0 = bm & 2047;      // seq offset
    const int j = tid >> 4;        // 0..15
    const int cch = tid & 15;      // 16B chunk
#pragma unroll
    for (int p = 0; p < 2; ++p) {
      if (wn == p) {
#pragma unroll
        for (int ni = 0; ni < 6; ++ni) {
          int nl = ni * 16 + l16;  // row within 96
          float bias_v = bv[nloc0 + p * 96 + nl];
#pragma unroll
          for (int mi = 0; mi < 4; ++mi)
#pragma unroll
            for (int r = 0; r < 4; ++r)
              Sh[nl * 136 + wm * 64 + mi * 16 + quad * 4 + r] =
                  f32_to_bf16(acc[mi][ni][r] + bias_v);
        }
      }
      __syncthreads();
#pragma unroll
      for (int it = 0; it < 6; ++it) {
        int row = it * 16 + j;
        int nv = nloc0 + p * 96 + row;
        int h2 = nv >> 6, dcol = nv & 63;
        uint4 v = *(const uint4*)(&Sh[row * 136 + cch * 8]);
        *(uint4*)(&Vt[((size_t)((bb * Hn + h2) * 64 + dcol)) * Sn + s0 + cch * 8]) = v;
      }
      __syncthreads();
    }
  }
}

// ---------------- flash attention (mixed softmax + relu^2) ----------------
// Scores computed TRANSPOSED (S^T = K Q^T) so the PV B-operand is built from
// C-layout fragments with permlane swaps — no P round-trip through LDS.
// Softmax denom via ones-row MFMA. XOR-swizzled LDS (conflict-free DMA+b128).
// launch_bounds(256,3): grid 768 = exactly 3 blocks/CU, one dispatch round.
__global__ __launch_bounds__(256, 3) void k_attn(
    const unsigned short* __restrict__ Qb, const unsigned short* __restrict__ Kb,
    const unsigned short* __restrict__ Vt, const float* __restrict__ wmix,
    unsigned short* __restrict__ Ctx) {
  __shared__ unsigned short Ks[128 * 64];
  __shared__ unsigned short Vs[64 * 128];

  const int tid = threadIdx.x;
  const int wave = tid >> 6, lane = tid & 63;
  const int quad = lane >> 4, l16 = lane & 15;
  const int l8 = l16 & 7;
  const int qt = blockIdx.x;   // 16 q-tiles
  const int bh = blockIdx.y;   // 48 = B*H
  const int b = bh / Hn, h = bh % Hn;

  const unsigned short* Qg = Qb + (size_t)(b * Sn + qt * 128) * Dm + h * 64;
  const unsigned short* Kg = Kb + (size_t)(b * Sn) * Dm + h * 64;
  const unsigned short* Vg = Vt + (size_t)bh * 64 * Sn;

  const int krr = lane >> 3, kcc = lane & 7;
  const int kchunk = kcc ^ krr;
  const int vrr = lane >> 4, vcc = lane & 15;

#pragma unroll
  for (int i = 0; i < 4; ++i) {
    int t = wave * 4 + i;
    gload_lds16(Qg + (size_t)(t * 8 + krr) * Dm + kchunk * 8, &Ks[t * 512]);
  }
  __syncthreads();
  short8 qf[2][2];
#pragma unroll
  for (int mi = 0; mi < 2; ++mi)
#pragma unroll
    for (int ks = 0; ks < 2; ++ks)
      qf[mi][ks] = *(const short8*)(
          &Ks[(wave * 32 + mi * 16 + l16) * 64 + (((ks * 4 + quad) ^ l8) << 3)]);
  __syncthreads();

  const f32x4 kZero = {0.f, 0.f, 0.f, 0.f};
  short8 ones;
#pragma unroll
  for (int i = 0; i < 8; ++i) ones[i] = (short)0x3F80;  // bf16(1.0)

  f32x4 acc_s[2][4], acc_r2[2][4], lacc[2];
#pragma unroll
  for (int i = 0; i < 2; ++i) {
#pragma unroll
    for (int j = 0; j < 4; ++j)
#pragma unroll
      for (int r = 0; r < 4; ++r) { acc_s[i][j][r] = 0.f; acc_r2[i][j][r] = 0.f; }
#pragma unroll
    for (int r = 0; r < 4; ++r) lacc[i][r] = 0.f;
  }

  for (int kt = 0; kt < 16; ++kt) {
#pragma unroll
    for (int i = 0; i < 4; ++i) {
      int t = wave * 4 + i;
      gload_lds16(Kg + (size_t)(kt * 128 + t * 8 + krr) * Dm + kchunk * 8, &Ks[t * 512]);
    }
#pragma unroll
    for (int i = 0; i < 4; ++i) {
      int t = wave * 4 + i;
      int vrow = t * 4 + vrr;
      int vch = vcc ^ ((4 * i + vrr) & 15);
      gload_lds16(Vg + (size_t)vrow * Sn + kt * 128 + vch * 8, &Vs[t * 512]);
    }
    __syncthreads();

#pragma unroll
    for (int c = 0; c < 4; ++c) {
      short8 kf[2][2];
#pragma unroll
      for (int t2 = 0; t2 < 2; ++t2)
#pragma unroll
        for (int ks = 0; ks < 2; ++ks)
          kf[t2][ks] = *(const short8*)(
              &Ks[((c * 2 + t2) * 16 + l16) * 64 + (((ks * 4 + quad) ^ l8) << 3)]);

      f32x4 sacc[2][2];
#pragma unroll
      for (int mi = 0; mi < 2; ++mi)
#pragma unroll
        for (int t2 = 0; t2 < 2; ++t2)
          sacc[mi][t2] = mfma_bf16(kf[t2][1], qf[mi][1],
                                   mfma_bf16(kf[t2][0], qf[mi][0], kZero));

      short8 vf[4];
#pragma unroll
      for (int nv = 0; nv < 4; ++nv)
        vf[nv] = *(const short8*)(
            &Vs[(nv * 16 + l16) * 128 + (((c * 4 + quad) ^ l16) << 3)]);

#pragma unroll
      for (int mi = 0; mi < 2; ++mi) {
        f32x4 s0 = sacc[mi][0], s1 = sacc[mi][1];
        float p1a[4], p1b[4], p2a[4], p2b[4];
#pragma unroll
        for (int r = 0; r < 4; ++r) {
          p1a[r] = __builtin_amdgcn_exp2f(s0[r]);
          p1b[r] = __builtin_amdgcn_exp2f(s1[r]);
          float t0 = fmaxf(s0[r], 0.f), t1 = fmaxf(s1[r], 0.f);
          p2a[r] = t0 * t0;
          p2b[r] = t1 * t1;
        }
        short8 pf1 = transpose_to_bfrag(cvt_pk_bf16(p1a[0], p1a[1]),
                                        cvt_pk_bf16(p1a[2], p1a[3]),
                                        cvt_pk_bf16(p1b[0], p1b[1]),
                                        cvt_pk_bf16(p1b[2], p1b[3]));
        short8 pf2 = transpose_to_bfrag(cvt_pk_bf16(p2a[0], p2a[1]),
                                        cvt_pk_bf16(p2a[2], p2a[3]),
                                        cvt_pk_bf16(p2b[0], p2b[1]),
                                        cvt_pk_bf16(p2b[2], p2b[3]));
#pragma unroll
        for (int nv = 0; nv < 4; ++nv) {
          acc_s[mi][nv] = mfma_bf16(vf[nv], pf1, acc_s[mi][nv]);
          acc_r2[mi][nv] = mfma_bf16(vf[nv], pf2, acc_r2[mi][nv]);
        }
        lacc[mi] = mfma_bf16(ones, pf1, lacc[mi]);  // D[*][q] = sum_k p1
      }
    }
    __syncthreads();
  }

  float w0 = wmix[0], w1 = wmix[1];
  float e0 = __expf(w0), e1 = __expf(w1);
  float mix0 = e0 / (e0 + e1);
  float mix1 = (e1 / (e0 + e1)) * kR2Fix;  // undo (log2e)^2 in relu^2 branch

#pragma unroll
  for (int mi = 0; mi < 2; ++mi) {
    float a0 = mix0 / lacc[mi][0];
    int srow = qt * 128 + wave * 32 + mi * 16 + l16;
#pragma unroll
    for (int nv = 0; nv < 4; ++nv) {
      float v0 = fmaf(acc_s[mi][nv][0], a0, mix1 * acc_r2[mi][nv][0]);
      float v1 = fmaf(acc_s[mi][nv][1], a0, mix1 * acc_r2[mi][nv][1]);
      float v2 = fmaf(acc_s[mi][nv][2], a0, mix1 * acc_r2[mi][nv][2]);
      float v3 = fmaf(acc_s[mi][nv][3], a0, mix1 * acc_r2[mi][nv][3]);
      uint2 o;
      o.x = cvt_pk_bf16(v0, v1);
      o.y = cvt_pk_bf16(v2, v3);
      *(uint2*)(&Ctx[(size_t)(b * Sn + srow) * Dm + h * 64 + nv * 16 + quad * 4]) = o;
    }
  }
}

// ---------------- output projection GEMM (fp32 out) ----------------
__global__ __launch_bounds__(256, 3) void k_gemm_out(
    const unsigned short* __restrict__ Abf, const unsigned short* __restrict__ W,
    const float* __restrict__ bias, float* __restrict__ out) {
  __shared__ unsigned short As[128 * 32];
  __shared__ unsigned short Bs[128 * 32];

  const int tid = threadIdx.x;
  const int wave = tid >> 6, lane = tid & 63;
  const int wm = wave >> 1, wn = wave & 1;
  const int quad = lane >> 4, l16 = lane & 15;
  const int bm = blockIdx.y * 128, bn = blockIdx.x * 128;

  const int sr = lane >> 2;
  const int sc = (lane & 3) * 8;
  const unsigned short* gA0 = Abf + (size_t)(bm + (wave * 2 + 0) * 16 + sr) * Dm + sc;
  const unsigned short* gA1 = Abf + (size_t)(bm + (wave * 2 + 1) * 16 + sr) * Dm + sc;
  const unsigned short* gB0 = W + (size_t)(bn + (wave * 2 + 0) * 16 + sr) * Dm + sc;
  const unsigned short* gB1 = W + (size_t)(bn + (wave * 2 + 1) * 16 + sr) * Dm + sc;
  unsigned short* lA0 = &As[(wave * 2 + 0) * 512];
  unsigned short* lA1 = &As[(wave * 2 + 1) * 512];
  unsigned short* lB0 = &Bs[(wave * 2 + 0) * 512];
  unsigned short* lB1 = &Bs[(wave * 2 + 1) * 512];

  f32x4 acc[4][4];
#pragma unroll
  for (int i = 0; i < 4; ++i)
#pragma unroll
    for (int j = 0; j < 4; ++j)
#pragma unroll
      for (int r = 0; r < 4; ++r) acc[i][j][r] = 0.f;

  for (int kk = 0; kk < Dm; kk += 32) {
    gload_lds16(gA0 + kk, lA0);
    gload_lds16(gA1 + kk, lA1);
    gload_lds16(gB0 + kk, lB0);
    gload_lds16(gB1 + kk, lB1);
    __syncthreads();
    short8 af[4], bf[4];
#pragma unroll
    for (int mi = 0; mi < 4; ++mi)
      af[mi] = *(const short8*)(&As[(wm * 64 + mi * 16 + l16) * 32 + quad * 8]);
#pragma unroll
    for (int ni = 0; ni < 4; ++ni)
      bf[ni] = *(const short8*)(&Bs[(wn * 64 + ni * 16 + l16) * 32 + quad * 8]);
#pragma unroll
    for (int mi = 0; mi < 4; ++mi)
#pragma unroll
      for (int ni = 0; ni < 4; ++ni)
        acc[mi][ni] = mfma_bf16(af[mi], bf[ni], acc[mi][ni]);
    __syncthreads();
  }

#pragma unroll
  for (int ni = 0; ni < 4; ++ni) {
    int n = bn + wn * 64 + ni * 16 + l16;
    float bias_v = bias[n];
#pragma unroll
    for (int mi = 0; mi < 4; ++mi) {
#pragma unroll
      for (int r = 0; r < 4; ++r) {
        int m = bm + wm * 64 + mi * 16 + quad * 4 + r;
        out[(size_t)m * Dm + n] = acc[mi][ni][r] + bias_v;
      }
    }
  }
}

extern "C" void kernel_launch(void* const* d_in, const int* in_sizes, int n_in,
                              void* d_out, int out_size, void* d_ws, size_t ws_size,
                              hipStream_t stream) {
  const float* hs = (const float*)d_in[0];
  const float* Wq = (const float*)d_in[1];
  const float* bq = (const float*)d_in[2];
  const float* Wk = (const float*)d_in[3];
  const float* bk = (const float*)d_in[4];
  const float* Wv = (const float*)d_in[5];
  const float* bv = (const float*)d_in[6];
  const float* Wo = (const float*)d_in[7];
  const float* bo = (const float*)d_in[8];
  const float* wmix = (const float*)d_in[9];

  unsigned short* hbf = (unsigned short*)d_ws;          // 8192*768
  unsigned short* wbf = hbf + (size_t)Mn * Dm;          // 4*768*768 ([Wq;Wk;Wv;Wo])
  unsigned short* Qb  = wbf + (size_t)4 * Dm * Dm;      // 8192*768
  unsigned short* Kb  = Qb + (size_t)Mn * Dm;           // 8192*768
  unsigned short* Vt  = Kb + (size_t)Mn * Dm;           // 48*64*2048
  unsigned short* Ctx = hbf;                            // reuse (hbf dead after QKV)

  k_cast_hidden<<<dim3(6144), dim3(256), 0, stream>>>(hs, hbf);
  k_cast_w<<<dim3(576, 4), dim3(256), 0, stream>>>(Wq, Wk, Wv, Wo, wbf);
  k_gemm_qkv<<<dim3(12, 64), dim3(256), 0, stream>>>(hbf, wbf, bq, bk, bv, Qb, Kb, Vt);
  k_attn<<<dim3(16, 48), dim3(256), 0, stream>>>(Qb, Kb, Vt, wmix, Ctx);
  k_gemm_out<<<dim3(6, 64), dim3(256), 0, stream>>>(Ctx, wbf + (size_t)3 * Dm * Dm, bo,
                                                    (float*)d_out);
}

// Round 7
// 257.734 us; speedup vs baseline: 1.5614x; 1.0062x over previous
//
#include <hip/hip_runtime.h>

#define DEV __device__ __forceinline__

typedef __attribute__((ext_vector_type(8))) short short8;
typedef __attribute__((ext_vector_type(4))) float f32x4;
typedef __attribute__((ext_vector_type(2))) unsigned int u32x2;
typedef __attribute__((ext_vector_type(4))) unsigned int u32x4;

constexpr int Dm = 768;   // model dim
constexpr int Sn = 2048;  // seq len
constexpr int Bn = 4;     // batch
constexpr int Hn = 12;    // heads
constexpr int Mn = Bn * Sn;  // 8192 rows

// Q is pre-scaled by 0.125*log2(e) so scores come out as s*log2(e):
// p1 = exp2(sacc) = e^s ; p2 = relu(sacc)^2 = (log2e)^2 * relu(s)^2
constexpr float kQScale = 0.18033688011112043f;     // 0.125 * log2(e)
constexpr float kR2Fix  = 0.4804530139182014f;      // 1 / (log2(e))^2

DEV unsigned short f32_to_bf16(float f) {
  unsigned int u = __float_as_uint(f);
  u = (u + 0x7fffu + ((u >> 16) & 1u)) >> 16;
  return (unsigned short)u;
}

// gfx950: pack two fp32 -> bf16x2 dword in ONE VALU op (RNE).
DEV unsigned cvt_pk_bf16(float lo, float hi) {
  unsigned d;
  asm("v_cvt_pk_bf16_f32 %0, %1, %2" : "=v"(d) : "v"(lo), "v"(hi));
  return d;
}

DEV f32x4 mfma_bf16(short8 a, short8 b, f32x4 c) {
  return __builtin_amdgcn_mfma_f32_16x16x32_bf16(a, b, c, 0, 0, 0);
}

// async global->LDS, 16B per lane; LDS dest = wave-uniform base + lane*16
DEV void gload_lds16(const void* g, void* l) {
  __builtin_amdgcn_global_load_lds(
      (__attribute__((address_space(1))) const unsigned int*)g,
      (__attribute__((address_space(3))) unsigned int*)l, 16, 0, 0);
}

// Transform two 16x16 S^T C-layout tiles (packed as bf16 dwords) into one
// B-operand fragment for mfma_16x16x32 (K=32 keys spanning both tiles).
DEV short8 transpose_to_bfrag(unsigned xd0, unsigned xd1, unsigned yd0, unsigned yd1) {
  u32x2 a0 = __builtin_amdgcn_permlane32_swap(xd0, yd0, false, false);
  u32x2 b0 = __builtin_amdgcn_permlane16_swap(a0[0], a0[1], false, false);
  u32x2 a1 = __builtin_amdgcn_permlane32_swap(xd1, yd1, false, false);
  u32x2 b1 = __builtin_amdgcn_permlane16_swap(a1[0], a1[1], false, false);
  u32x4 f = {b0[0], b1[0], b0[1], b1[1]};
  return __builtin_bit_cast(short8, f);
}

// ---------------- cast kernels ----------------
__global__ __launch_bounds__(256) void k_cast_hidden(const float* __restrict__ src,
                                                     unsigned short* __restrict__ dst) {
  int i = blockIdx.x * 256 + threadIdx.x;
  float4 v = ((const float4*)src)[i];
  ushort4 o;
  o.x = f32_to_bf16(v.x); o.y = f32_to_bf16(v.y);
  o.z = f32_to_bf16(v.z); o.w = f32_to_bf16(v.w);
  ((ushort4*)dst)[i] = o;
}

__global__ __launch_bounds__(256) void k_cast_w(const float* __restrict__ Wq,
                                                const float* __restrict__ Wk,
                                                const float* __restrict__ Wv,
                                                const float* __restrict__ Wo,
                                                unsigned short* __restrict__ wbf) {
  const float* src = (blockIdx.y == 0) ? Wq : (blockIdx.y == 1) ? Wk
                   : (blockIdx.y == 2) ? Wv : Wo;
  unsigned short* dst = wbf + (size_t)blockIdx.y * (Dm * Dm);
  int i = blockIdx.x * 256 + threadIdx.x;
  float4 v = ((const float4*)src)[i];
  ushort4 o;
  o.x = f32_to_bf16(v.x); o.y = f32_to_bf16(v.y);
  o.z = f32_to_bf16(v.z); o.w = f32_to_bf16(v.w);
  ((ushort4*)dst)[i] = o;
}

// ---------------- merged QKV projection GEMM ----------------
// One GEMM over stacked W' = [Wq;Wk;Wv] (N'=2304). Tile 128(M) x 192(N),
// grid 12x64 = 768 blocks = exactly one round at 3 blocks/CU.
__global__ __launch_bounds__(256, 3) void k_gemm_qkv(
    const unsigned short* __restrict__ Abf, const unsigned short* __restrict__ wbf,
    const float* __restrict__ bq, const float* __restrict__ bk, const float* __restrict__ bv,
    unsigned short* __restrict__ Qb, unsigned short* __restrict__ Kb,
    unsigned short* __restrict__ Vt) {
  // union: staging As[128x32]=4096 + Bs[192x32]=6144 shorts (20.5 KB)
  //        | V-transpose tile [96][136] = 13056 shorts (26 KB)
  __shared__ unsigned short Sh[96 * 136];
  unsigned short* As = Sh;
  unsigned short* Bs = Sh + 4096;

  const int tid = threadIdx.x;
  const int wave = tid >> 6, lane = tid & 63;
  const int wm = wave >> 1, wn = wave & 1;
  const int quad = lane >> 4, l16 = lane & 15;
  const int bm = blockIdx.y * 128, bn = blockIdx.x * 192;
  const int seg = blockIdx.x >> 2;            // 0=Q 1=K 2=V
  const int nloc0 = (blockIdx.x & 3) * 192;   // column offset within 768

  const int sr = lane >> 2;
  const int sc = (lane & 3) * 8;
  const unsigned short* gA0 = Abf + (size_t)(bm + (wave * 2 + 0) * 16 + sr) * Dm + sc;
  const unsigned short* gA1 = Abf + (size_t)(bm + (wave * 2 + 1) * 16 + sr) * Dm + sc;
  const unsigned short* gB0 = wbf + (size_t)(bn + (wave * 3 + 0) * 16 + sr) * Dm + sc;
  const unsigned short* gB1 = wbf + (size_t)(bn + (wave * 3 + 1) * 16 + sr) * Dm + sc;
  const unsigned short* gB2 = wbf + (size_t)(bn + (wave * 3 + 2) * 16 + sr) * Dm + sc;
  unsigned short* lA0 = &As[(wave * 2 + 0) * 512];
  unsigned short* lA1 = &As[(wave * 2 + 1) * 512];
  unsigned short* lB0 = &Bs[(wave * 3 + 0) * 512];
  unsigned short* lB1 = &Bs[(wave * 3 + 1) * 512];
  unsigned short* lB2 = &Bs[(wave * 3 + 2) * 512];

  f32x4 acc[4][6];
#pragma unroll
  for (int i = 0; i < 4; ++i)
#pragma unroll
    for (int j = 0; j < 6; ++j)
#pragma unroll
      for (int r = 0; r < 4; ++r) acc[i][j][r] = 0.f;

  for (int kk = 0; kk < Dm; kk += 32) {
    gload_lds16(gA0 + kk, lA0);
    gload_lds16(gA1 + kk, lA1);
    gload_lds16(gB0 + kk, lB0);
    gload_lds16(gB1 + kk, lB1);
    gload_lds16(gB2 + kk, lB2);
    __syncthreads();
    short8 af[4], bf[6];
#pragma unroll
    for (int mi = 0; mi < 4; ++mi)
      af[mi] = *(const short8*)(&As[(wm * 64 + mi * 16 + l16) * 32 + quad * 8]);
#pragma unroll
    for (int ni = 0; ni < 6; ++ni)
      bf[ni] = *(const short8*)(&Bs[(wn * 96 + ni * 16 + l16) * 32 + quad * 8]);
#pragma unroll
    for (int mi = 0; mi < 4; ++mi)
#pragma unroll
      for (int ni = 0; ni < 6; ++ni)
        acc[mi][ni] = mfma_bf16(af[mi], bf[ni], acc[mi][ni]);
    __syncthreads();
  }

  if (seg != 2) {
    const float* bias = (seg == 0) ? bq : bk;
    unsigned short* Out = (seg == 0) ? Qb : Kb;
    const float scale = (seg == 0) ? kQScale : 1.0f;
#pragma unroll
    for (int ni = 0; ni < 6; ++ni) {
      int n = nloc0 + wn * 96 + ni * 16 + l16;
      float bias_v = bias[n];
#pragma unroll
      for (int mi = 0; mi < 4; ++mi) {
#pragma unroll
        for (int r = 0; r < 4; ++r) {
          int m = bm + wm * 64 + mi * 16 + quad * 4 + r;
          Out[(size_t)m * Dm + n] = f32_to_bf16((acc[mi][ni][r] + bias_v) * scale);
        }
      }
    }
  } else {
    // V: two-pass LDS transpose, then coalesced 256B-row stores of V^T.
    const int bb = bm >> 11;       // batch
    const int s0 = bm & 2047;      // seq offset
    const int j = tid >> 4;        // 0..15
    const int cch = tid & 15;      // 16B chunk
#pragma unroll
    for (int p = 0; p < 2; ++p) {
      if (wn == p) {
#pragma unroll
        for (int ni = 0; ni < 6; ++ni) {
          int nl = ni * 16 + l16;  // row within 96
          float bias_v = bv[nloc0 + p * 96 + nl];
#pragma unroll
          for (int mi = 0; mi < 4; ++mi)
#pragma unroll
            for (int r = 0; r < 4; ++r)
              Sh[nl * 136 + wm * 64 + mi * 16 + quad * 4 + r] =
                  f32_to_bf16(acc[mi][ni][r] + bias_v);
        }
      }
      __syncthreads();
#pragma unroll
      for (int it = 0; it < 6; ++it) {
        int row = it * 16 + j;
        int nv = nloc0 + p * 96 + row;
        int h2 = nv >> 6, dcol = nv & 63;
        uint4 v = *(const uint4*)(&Sh[row * 136 + cch * 8]);
        *(uint4*)(&Vt[((size_t)((bb * Hn + h2) * 64 + dcol)) * Sn + s0 + cch * 8]) = v;
      }
      __syncthreads();
    }
  }
}

// ---------------- flash attention (mixed softmax + relu^2) ----------------
// Scores computed TRANSPOSED (S^T = K Q^T); PV B-operand built in-register
// via permlane swaps. Softmax denom via ones-row MFMA. XOR-swizzled LDS.
// Grid: linear 768 with XCD-aware decode — blockIdx%8 (=XCD under round-robin
// dispatch) picks a contiguous group of 6 bh, so each XCD's L2 only holds
// 6 x 512KB = 3MB of K/V (fits 4MiB) instead of thrashing all 48 bh.
__global__ __launch_bounds__(256, 3) void k_attn(
    const unsigned short* __restrict__ Qb, const unsigned short* __restrict__ Kb,
    const unsigned short* __restrict__ Vt, const float* __restrict__ wmix,
    unsigned short* __restrict__ Ctx) {
  __shared__ unsigned short Ks[128 * 64];
  __shared__ unsigned short Vs[64 * 128];

  const int tid = threadIdx.x;
  const int wave = tid >> 6, lane = tid & 63;
  const int quad = lane >> 4, l16 = lane & 15;
  const int l8 = l16 & 7;
  // XCD-aware swizzle: lin = qt*48 + s ; bh = (s&7)*6 + (s>>3)
  const int lin = blockIdx.x;
  const int qt = lin / 48;
  const int s = lin % 48;
  const int bh = (s & 7) * 6 + (s >> 3);
  const int b = bh / Hn, h = bh % Hn;

  const unsigned short* Qg = Qb + (size_t)(b * Sn + qt * 128) * Dm + h * 64;
  const unsigned short* Kg = Kb + (size_t)(b * Sn) * Dm + h * 64;
  const unsigned short* Vg = Vt + (size_t)bh * 64 * Sn;

  const int krr = lane >> 3, kcc = lane & 7;
  const int kchunk = kcc ^ krr;
  const int vrr = lane >> 4, vcc = lane & 15;

#pragma unroll
  for (int i = 0; i < 4; ++i) {
    int t = wave * 4 + i;
    gload_lds16(Qg + (size_t)(t * 8 + krr) * Dm + kchunk * 8, &Ks[t * 512]);
  }
  __syncthreads();
  short8 qf[2][2];
#pragma unroll
  for (int mi = 0; mi < 2; ++mi)
#pragma unroll
    for (int ks = 0; ks < 2; ++ks)
      qf[mi][ks] = *(const short8*)(
          &Ks[(wave * 32 + mi * 16 + l16) * 64 + (((ks * 4 + quad) ^ l8) << 3)]);
  __syncthreads();

  const f32x4 kZero = {0.f, 0.f, 0.f, 0.f};
  short8 ones;
#pragma unroll
  for (int i = 0; i < 8; ++i) ones[i] = (short)0x3F80;  // bf16(1.0)

  f32x4 acc_s[2][4], acc_r2[2][4], lacc[2];
#pragma unroll
  for (int i = 0; i < 2; ++i) {
#pragma unroll
    for (int j = 0; j < 4; ++j)
#pragma unroll
      for (int r = 0; r < 4; ++r) { acc_s[i][j][r] = 0.f; acc_r2[i][j][r] = 0.f; }
#pragma unroll
    for (int r = 0; r < 4; ++r) lacc[i][r] = 0.f;
  }

  for (int kt = 0; kt < 16; ++kt) {
#pragma unroll
    for (int i = 0; i < 4; ++i) {
      int t = wave * 4 + i;
      gload_lds16(Kg + (size_t)(kt * 128 + t * 8 + krr) * Dm + kchunk * 8, &Ks[t * 512]);
    }
#pragma unroll
    for (int i = 0; i < 4; ++i) {
      int t = wave * 4 + i;
      int vrow = t * 4 + vrr;
      int vch = vcc ^ ((4 * i + vrr) & 15);
      gload_lds16(Vg + (size_t)vrow * Sn + kt * 128 + vch * 8, &Vs[t * 512]);
    }
    __syncthreads();

#pragma unroll
    for (int c = 0; c < 4; ++c) {
      short8 kf[2][2];
#pragma unroll
      for (int t2 = 0; t2 < 2; ++t2)
#pragma unroll
        for (int ks = 0; ks < 2; ++ks)
          kf[t2][ks] = *(const short8*)(
              &Ks[((c * 2 + t2) * 16 + l16) * 64 + (((ks * 4 + quad) ^ l8) << 3)]);

      f32x4 sacc[2][2];
#pragma unroll
      for (int mi = 0; mi < 2; ++mi)
#pragma unroll
        for (int t2 = 0; t2 < 2; ++t2)
          sacc[mi][t2] = mfma_bf16(kf[t2][1], qf[mi][1],
                                   mfma_bf16(kf[t2][0], qf[mi][0], kZero));

      short8 vf[4];
#pragma unroll
      for (int nv = 0; nv < 4; ++nv)
        vf[nv] = *(const short8*)(
            &Vs[(nv * 16 + l16) * 128 + (((c * 4 + quad) ^ l16) << 3)]);

#pragma unroll
      for (int mi = 0; mi < 2; ++mi) {
        f32x4 s0 = sacc[mi][0], s1 = sacc[mi][1];
        float p1a[4], p1b[4], p2a[4], p2b[4];
#pragma unroll
        for (int r = 0; r < 4; ++r) {
          p1a[r] = __builtin_amdgcn_exp2f(s0[r]);
          p1b[r] = __builtin_amdgcn_exp2f(s1[r]);
          float t0 = fmaxf(s0[r], 0.f), t1 = fmaxf(s1[r], 0.f);
          p2a[r] = t0 * t0;
          p2b[r] = t1 * t1;
        }
        short8 pf1 = transpose_to_bfrag(cvt_pk_bf16(p1a[0], p1a[1]),
                                        cvt_pk_bf16(p1a[2], p1a[3]),
                                        cvt_pk_bf16(p1b[0], p1b[1]),
                                        cvt_pk_bf16(p1b[2], p1b[3]));
        short8 pf2 = transpose_to_bfrag(cvt_pk_bf16(p2a[0], p2a[1]),
                                        cvt_pk_bf16(p2a[2], p2a[3]),
                                        cvt_pk_bf16(p2b[0], p2b[1]),
                                        cvt_pk_bf16(p2b[2], p2b[3]));
#pragma unroll
        for (int nv = 0; nv < 4; ++nv) {
          acc_s[mi][nv] = mfma_bf16(vf[nv], pf1, acc_s[mi][nv]);
          acc_r2[mi][nv] = mfma_bf16(vf[nv], pf2, acc_r2[mi][nv]);
        }
        lacc[mi] = mfma_bf16(ones, pf1, lacc[mi]);  // D[*][q] = sum_k p1
      }
    }
    __syncthreads();
  }

  float w0 = wmix[0], w1 = wmix[1];
  float e0 = __expf(w0), e1 = __expf(w1);
  float mix0 = e0 / (e0 + e1);
  float mix1 = (e1 / (e0 + e1)) * kR2Fix;  // undo (log2e)^2 in relu^2 branch

#pragma unroll
  for (int mi = 0; mi < 2; ++mi) {
    float a0 = mix0 / lacc[mi][0];
    int srow = qt * 128 + wave * 32 + mi * 16 + l16;
#pragma unroll
    for (int nv = 0; nv < 4; ++nv) {
      float v0 = fmaf(acc_s[mi][nv][0], a0, mix1 * acc_r2[mi][nv][0]);
      float v1 = fmaf(acc_s[mi][nv][1], a0, mix1 * acc_r2[mi][nv][1]);
      float v2 = fmaf(acc_s[mi][nv][2], a0, mix1 * acc_r2[mi][nv][2]);
      float v3 = fmaf(acc_s[mi][nv][3], a0, mix1 * acc_r2[mi][nv][3]);
      uint2 o;
      o.x = cvt_pk_bf16(v0, v1);
      o.y = cvt_pk_bf16(v2, v3);
      *(uint2*)(&Ctx[(size_t)(b * Sn + srow) * Dm + h * 64 + nv * 16 + quad * 4]) = o;
    }
  }
}

// ---------------- output projection GEMM (fp32 out) ----------------
__global__ __launch_bounds__(256, 3) void k_gemm_out(
    const unsigned short* __restrict__ Abf, const unsigned short* __restrict__ W,
    const float* __restrict__ bias, float* __restrict__ out) {
  __shared__ unsigned short As[128 * 32];
  __shared__ unsigned short Bs[128 * 32];

  const int tid = threadIdx.x;
  const int wave = tid >> 6, lane = tid & 63;
  const int wm = wave >> 1, wn = wave & 1;
  const int quad = lane >> 4, l16 = lane & 15;
  const int bm = blockIdx.y * 128, bn = blockIdx.x * 128;

  const int sr = lane >> 2;
  const int sc = (lane & 3) * 8;
  const unsigned short* gA0 = Abf + (size_t)(bm + (wave * 2 + 0) * 16 + sr) * Dm + sc;
  const unsigned short* gA1 = Abf + (size_t)(bm + (wave * 2 + 1) * 16 + sr) * Dm + sc;
  const unsigned short* gB0 = W + (size_t)(bn + (wave * 2 + 0) * 16 + sr) * Dm + sc;
  const unsigned short* gB1 = W + (size_t)(bn + (wave * 2 + 1) * 16 + sr) * Dm + sc;
  unsigned short* lA0 = &As[(wave * 2 + 0) * 512];
  unsigned short* lA1 = &As[(wave * 2 + 1) * 512];
  unsigned short* lB0 = &Bs[(wave * 2 + 0) * 512];
  unsigned short* lB1 = &Bs[(wave * 2 + 1) * 512];

  f32x4 acc[4][4];
#pragma unroll
  for (int i = 0; i < 4; ++i)
#pragma unroll
    for (int j = 0; j < 4; ++j)
#pragma unroll
      for (int r = 0; r < 4; ++r) acc[i][j][r] = 0.f;

  for (int kk = 0; kk < Dm; kk += 32) {
    gload_lds16(gA0 + kk, lA0);
    gload_lds16(gA1 + kk, lA1);
    gload_lds16(gB0 + kk, lB0);
    gload_lds16(gB1 + kk, lB1);
    __syncthreads();
    short8 af[4], bf[4];
#pragma unroll
    for (int mi = 0; mi < 4; ++mi)
      af[mi] = *(const short8*)(&As[(wm * 64 + mi * 16 + l16) * 32 + quad * 8]);
#pragma unroll
    for (int ni = 0; ni < 4; ++ni)
      bf[ni] = *(const short8*)(&Bs[(wn * 64 + ni * 16 + l16) * 32 + quad * 8]);
#pragma unroll
    for (int mi = 0; mi < 4; ++mi)
#pragma unroll
      for (int ni = 0; ni < 4; ++ni)
        acc[mi][ni] = mfma_bf16(af[mi], bf[ni], acc[mi][ni]);
    __syncthreads();
  }

#pragma unroll
  for (int ni = 0; ni < 4; ++ni) {
    int n = bn + wn * 64 + ni * 16 + l16;
    float bias_v = bias[n];
#pragma unroll
    for (int mi = 0; mi < 4; ++mi) {
#pragma unroll
      for (int r = 0; r < 4; ++r) {
        int m = bm + wm * 64 + mi * 16 + quad * 4 + r;
        out[(size_t)m * Dm + n] = acc[mi][ni][r] + bias_v;
      }
    }
  }
}

extern "C" void kernel_launch(void* const* d_in, const int* in_sizes, int n_in,
                              void* d_out, int out_size, void* d_ws, size_t ws_size,
                              hipStream_t stream) {
  const float* hs = (const float*)d_in[0];
  const float* Wq = (const float*)d_in[1];
  const float* bq = (const float*)d_in[2];
  const float* Wk = (const float*)d_in[3];
  const float* bk = (const float*)d_in[4];
  const float* Wv = (const float*)d_in[5];
  const float* bv = (const float*)d_in[6];
  const float* Wo = (const float*)d_in[7];
  const float* bo = (const float*)d_in[8];
  const float* wmix = (const float*)d_in[9];

  unsigned short* hbf = (unsigned short*)d_ws;          // 8192*768
  unsigned short* wbf = hbf + (size_t)Mn * Dm;          // 4*768*768 ([Wq;Wk;Wv;Wo])
  unsigned short* Qb  = wbf + (size_t)4 * Dm * Dm;      // 8192*768
  unsigned short* Kb  = Qb + (size_t)Mn * Dm;           // 8192*768
  unsigned short* Vt  = Kb + (size_t)Mn * Dm;           // 48*64*2048
  unsigned short* Ctx = hbf;                            // reuse (hbf dead after QKV)

  k_cast_hidden<<<dim3(6144), dim3(256), 0, stream>>>(hs, hbf);
  k_cast_w<<<dim3(576, 4), dim3(256), 0, stream>>>(Wq, Wk, Wv, Wo, wbf);
  k_gemm_qkv<<<dim3(12, 64), dim3(256), 0, stream>>>(hbf, wbf, bq, bk, bv, Qb, Kb, Vt);
  k_attn<<<dim3(768), dim3(256), 0, stream>>>(Qb, Kb, Vt, wmix, Ctx);
  k_gemm_out<<<dim3(6, 64), dim3(256), 0, stream>>>(Ctx, wbf + (size_t)3 * Dm * Dm, bo,
                                                    (float*)d_out);
}

// Round 8
// 240.623 us; speedup vs baseline: 1.6724x; 1.0711x over previous
//
#include <hip/hip_runtime.h>

#define DEV __device__ __forceinline__

typedef __attribute__((ext_vector_type(8))) short short8;
typedef __attribute__((ext_vector_type(4))) float f32x4;
typedef __attribute__((ext_vector_type(2))) unsigned int u32x2;
typedef __attribute__((ext_vector_type(4))) unsigned int u32x4;

constexpr int Dm = 768;   // model dim
constexpr int Sn = 2048;  // seq len
constexpr int Bn = 4;     // batch
constexpr int Hn = 12;    // heads
constexpr int Mn = Bn * Sn;  // 8192 rows

// Q is pre-scaled by 0.125*log2(e) so scores come out as s*log2(e):
// p1 = exp2(sacc) = e^s ; p2 = relu(sacc)^2 = (log2e)^2 * relu(s)^2
constexpr float kQScale = 0.18033688011112043f;     // 0.125 * log2(e)
constexpr float kR2Fix  = 0.4804530139182014f;      // 1 / (log2(e))^2

DEV unsigned short f32_to_bf16(float f) {
  unsigned int u = __float_as_uint(f);
  u = (u + 0x7fffu + ((u >> 16) & 1u)) >> 16;
  return (unsigned short)u;
}

// gfx950: pack two fp32 -> bf16x2 dword in ONE VALU op (RNE).
DEV unsigned cvt_pk_bf16(float lo, float hi) {
  unsigned d;
  asm("v_cvt_pk_bf16_f32 %0, %1, %2" : "=v"(d) : "v"(lo), "v"(hi));
  return d;
}

DEV f32x4 mfma_bf16(short8 a, short8 b, f32x4 c) {
  return __builtin_amdgcn_mfma_f32_16x16x32_bf16(a, b, c, 0, 0, 0);
}

// async global->LDS, 16B per lane; LDS dest = wave-uniform base + lane*16
DEV void gload_lds16(const void* g, void* l) {
  __builtin_amdgcn_global_load_lds(
      (__attribute__((address_space(1))) const unsigned int*)g,
      (__attribute__((address_space(3))) unsigned int*)l, 16, 0, 0);
}

// Transform two 16x16 S^T C-layout tiles (packed as bf16 dwords) into one
// B-operand fragment for mfma_16x16x32 (K=32 keys spanning both tiles).
DEV short8 transpose_to_bfrag(unsigned xd0, unsigned xd1, unsigned yd0, unsigned yd1) {
  u32x2 a0 = __builtin_amdgcn_permlane32_swap(xd0, yd0, false, false);
  u32x2 b0 = __builtin_amdgcn_permlane16_swap(a0[0], a0[1], false, false);
  u32x2 a1 = __builtin_amdgcn_permlane32_swap(xd1, yd1, false, false);
  u32x2 b1 = __builtin_amdgcn_permlane16_swap(a1[0], a1[1], false, false);
  u32x4 f = {b0[0], b1[0], b0[1], b1[1]};
  return __builtin_bit_cast(short8, f);
}

// ---------------- merged cast kernel (one launch) ----------------
__global__ __launch_bounds__(256) void k_cast_all(
    const float* __restrict__ hs, const float* __restrict__ Wq,
    const float* __restrict__ Wk, const float* __restrict__ Wv,
    const float* __restrict__ Wo, unsigned short* __restrict__ hbf,
    unsigned short* __restrict__ wbf) {
  int bx = blockIdx.x;
  if (bx < 6144) {
    int i = bx * 256 + threadIdx.x;     // hidden: 6144*256 float4
    float4 v = ((const float4*)hs)[i];
    ushort4 o;
    o.x = f32_to_bf16(v.x); o.y = f32_to_bf16(v.y);
    o.z = f32_to_bf16(v.z); o.w = f32_to_bf16(v.w);
    ((ushort4*)hbf)[i] = o;
  } else {
    int i = (bx - 6144) * 256 + threadIdx.x;  // weights: 4*147456 float4
    int w = i / 147456;
    int off = i - w * 147456;
    const float* src = (w == 0) ? Wq : (w == 1) ? Wk : (w == 2) ? Wv : Wo;
    float4 v = ((const float4*)src)[off];
    ushort4 o;
    o.x = f32_to_bf16(v.x); o.y = f32_to_bf16(v.y);
    o.z = f32_to_bf16(v.z); o.w = f32_to_bf16(v.w);
    ((ushort4*)wbf)[w * 147456 + off] = o;
  }
}

// ---------------- merged QKV projection GEMM ----------------
// One GEMM over stacked W' = [Wq;Wk;Wv] (N'=2304). Tile 128(M) x 192(N),
// grid 12x64 = 768 blocks = exactly one round at 3 blocks/CU.
__global__ __launch_bounds__(256, 3) void k_gemm_qkv(
    const unsigned short* __restrict__ Abf, const unsigned short* __restrict__ wbf,
    const float* __restrict__ bq, const float* __restrict__ bk, const float* __restrict__ bv,
    unsigned short* __restrict__ Qb, unsigned short* __restrict__ Kb,
    unsigned short* __restrict__ Vt) {
  // union: staging As[128x32]=4096 + Bs[192x32]=6144 shorts (20.5 KB)
  //        | V-transpose tile [96][136] = 13056 shorts (26 KB)
  __shared__ unsigned short Sh[96 * 136];
  unsigned short* As = Sh;
  unsigned short* Bs = Sh + 4096;

  const int tid = threadIdx.x;
  const int wave = tid >> 6, lane = tid & 63;
  const int wm = wave >> 1, wn = wave & 1;
  const int quad = lane >> 4, l16 = lane & 15;
  const int bm = blockIdx.y * 128, bn = blockIdx.x * 192;
  const int seg = blockIdx.x >> 2;            // 0=Q 1=K 2=V
  const int nloc0 = (blockIdx.x & 3) * 192;   // column offset within 768

  const int sr = lane >> 2;
  const int sc = (lane & 3) * 8;
  const unsigned short* gA0 = Abf + (size_t)(bm + (wave * 2 + 0) * 16 + sr) * Dm + sc;
  const unsigned short* gA1 = Abf + (size_t)(bm + (wave * 2 + 1) * 16 + sr) * Dm + sc;
  const unsigned short* gB0 = wbf + (size_t)(bn + (wave * 3 + 0) * 16 + sr) * Dm + sc;
  const unsigned short* gB1 = wbf + (size_t)(bn + (wave * 3 + 1) * 16 + sr) * Dm + sc;
  const unsigned short* gB2 = wbf + (size_t)(bn + (wave * 3 + 2) * 16 + sr) * Dm + sc;
  unsigned short* lA0 = &As[(wave * 2 + 0) * 512];
  unsigned short* lA1 = &As[(wave * 2 + 1) * 512];
  unsigned short* lB0 = &Bs[(wave * 3 + 0) * 512];
  unsigned short* lB1 = &Bs[(wave * 3 + 1) * 512];
  unsigned short* lB2 = &Bs[(wave * 3 + 2) * 512];

  f32x4 acc[4][6];
#pragma unroll
  for (int i = 0; i < 4; ++i)
#pragma unroll
    for (int j = 0; j < 6; ++j)
#pragma unroll
      for (int r = 0; r < 4; ++r) acc[i][j][r] = 0.f;

  for (int kk = 0; kk < Dm; kk += 32) {
    gload_lds16(gA0 + kk, lA0);
    gload_lds16(gA1 + kk, lA1);
    gload_lds16(gB0 + kk, lB0);
    gload_lds16(gB1 + kk, lB1);
    gload_lds16(gB2 + kk, lB2);
    __syncthreads();
    short8 af[4], bf[6];
#pragma unroll
    for (int mi = 0; mi < 4; ++mi)
      af[mi] = *(const short8*)(&As[(wm * 64 + mi * 16 + l16) * 32 + quad * 8]);
#pragma unroll
    for (int ni = 0; ni < 6; ++ni)
      bf[ni] = *(const short8*)(&Bs[(wn * 96 + ni * 16 + l16) * 32 + quad * 8]);
#pragma unroll
    for (int mi = 0; mi < 4; ++mi)
#pragma unroll
      for (int ni = 0; ni < 6; ++ni)
        acc[mi][ni] = mfma_bf16(af[mi], bf[ni], acc[mi][ni]);
    __syncthreads();
  }

  if (seg != 2) {
    const float* bias = (seg == 0) ? bq : bk;
    unsigned short* Out = (seg == 0) ? Qb : Kb;
    const float scale = (seg == 0) ? kQScale : 1.0f;
#pragma unroll
    for (int ni = 0; ni < 6; ++ni) {
      int n = nloc0 + wn * 96 + ni * 16 + l16;
      float bias_v = bias[n];
#pragma unroll
      for (int mi = 0; mi < 4; ++mi) {
#pragma unroll
        for (int r = 0; r < 4; ++r) {
          int m = bm + wm * 64 + mi * 16 + quad * 4 + r;
          Out[(size_t)m * Dm + n] = f32_to_bf16((acc[mi][ni][r] + bias_v) * scale);
        }
      }
    }
  } else {
    // V: two-pass LDS transpose, then coalesced 256B-row stores of V^T.
    const int bb = bm >> 11;       // batch
    const int s0 = bm & 2047;      // seq offset
    const int j = tid >> 4;        // 0..15
    const int cch = tid & 15;      // 16B chunk
#pragma unroll
    for (int p = 0; p < 2; ++p) {
      if (wn == p) {
#pragma unroll
        for (int ni = 0; ni < 6; ++ni) {
          int nl = ni * 16 + l16;  // row within 96
          float bias_v = bv[nloc0 + p * 96 + nl];
#pragma unroll
          for (int mi = 0; mi < 4; ++mi)
#pragma unroll
            for (int r = 0; r < 4; ++r)
              Sh[nl * 136 + wm * 64 + mi * 16 + quad * 4 + r] =
                  f32_to_bf16(acc[mi][ni][r] + bias_v);
        }
      }
      __syncthreads();
#pragma unroll
      for (int it = 0; it < 6; ++it) {
        int row = it * 16 + j;
        int nv = nloc0 + p * 96 + row;
        int h2 = nv >> 6, dcol = nv & 63;
        uint4 v = *(const uint4*)(&Sh[row * 136 + cch * 8]);
        *(uint4*)(&Vt[((size_t)((bb * Hn + h2) * 64 + dcol)) * Sn + s0 + cch * 8]) = v;
      }
      __syncthreads();
    }
  }
}

// ---------------- flash attention (mixed softmax + relu^2) ----------------
// S^T = K Q^T; PV B-operand built in-register via permlane swaps; denom via
// ones-row MFMA; XCD-aware bh grouping (blockIdx%8 -> 6 contiguous bh).
// NEW: double-buffered 64-key K/V tiles (32 KB total, 3 blocks/CU) with the
// prefetch for kt+1 issued BEFORE compute of kt — the single end-of-iteration
// __syncthreads' vmcnt drain is then ~free (DMA landed during compute),
// removing the exposed global->LDS latency and one barrier per tile.
__global__ __launch_bounds__(256, 3) void k_attn(
    const unsigned short* __restrict__ Qb, const unsigned short* __restrict__ Kb,
    const unsigned short* __restrict__ Vt, const float* __restrict__ wmix,
    unsigned short* __restrict__ Ctx) {
  __shared__ unsigned short Ks[2][64 * 64];   // [buf][row(key)][dh] swizzled
  __shared__ unsigned short Vs[2][64 * 64];   // [buf][dh][key] swizzled

  const int tid = threadIdx.x;
  const int wave = tid >> 6, lane = tid & 63;
  const int quad = lane >> 4, l16 = lane & 15;
  const int l8 = l16 & 7;
  // XCD-aware swizzle: lin = qt*48 + s ; bh = (s&7)*6 + (s>>3)
  const int lin = blockIdx.x;
  const int qt = lin / 48;
  const int s = lin % 48;
  const int bh = (s & 7) * 6 + (s >> 3);
  const int b = bh / Hn, h = bh % Hn;

  const unsigned short* Qg = Qb + (size_t)(b * Sn + qt * 128) * Dm + h * 64;
  const unsigned short* Kg = Kb + (size_t)(b * Sn) * Dm + h * 64;
  const unsigned short* Vg = Vt + (size_t)bh * 64 * Sn;

  const int krr = lane >> 3, kcc = lane & 7;
  const int kchunk = kcc ^ krr;   // global 16B chunk fetched by this lane

  // ---- stage Q tile (128x64 = 16KB) across Ks[0]+Ks[1] as scratch ----
#pragma unroll
  for (int i = 0; i < 4; ++i) {
    int t = wave * 4 + i;  // 0..15 1KB blocks
    gload_lds16(Qg + (size_t)(t * 8 + krr) * Dm + kchunk * 8, &Ks[0][0] + t * 512);
  }
  __syncthreads();
  short8 qf[2][2];
#pragma unroll
  for (int mi = 0; mi < 2; ++mi)
#pragma unroll
    for (int ks = 0; ks < 2; ++ks)
      qf[mi][ks] = *(const short8*)(
          &Ks[wave >> 1][((wave & 1) * 32 + mi * 16 + l16) * 64 +
                         (((ks * 4 + quad) ^ l8) << 3)]);
  __syncthreads();  // protect Ks from kt0 staging until all qf reads done

  const f32x4 kZero = {0.f, 0.f, 0.f, 0.f};
  short8 ones;
#pragma unroll
  for (int i = 0; i < 8; ++i) ones[i] = (short)0x3F80;  // bf16(1.0)

  f32x4 acc_s[2][4], acc_r2[2][4], lacc[2];
#pragma unroll
  for (int i = 0; i < 2; ++i) {
#pragma unroll
    for (int j = 0; j < 4; ++j)
#pragma unroll
      for (int r = 0; r < 4; ++r) { acc_s[i][j][r] = 0.f; acc_r2[i][j][r] = 0.f; }
#pragma unroll
    for (int r = 0; r < 4; ++r) lacc[i][r] = 0.f;
  }

  // stage kt=0 into buf0
#pragma unroll
  for (int i = 0; i < 2; ++i) {
    int t = wave * 2 + i;  // 0..7
    gload_lds16(Kg + (size_t)(t * 8 + krr) * Dm + kchunk * 8, &Ks[0][t * 512]);
    gload_lds16(Vg + (size_t)(t * 8 + krr) * Sn + kchunk * 8, &Vs[0][t * 512]);
  }
  __syncthreads();  // buf0 ready

  for (int kt = 0; kt < 32; ++kt) {
    const int cur = kt & 1;
    // prefetch kt+1 into the other buffer; lands during compute below
    if (kt < 31) {
      const int nxt = cur ^ 1;
      const int kb = (kt + 1) * 64;
#pragma unroll
      for (int i = 0; i < 2; ++i) {
        int t = wave * 2 + i;
        gload_lds16(Kg + (size_t)(kb + t * 8 + krr) * Dm + kchunk * 8, &Ks[nxt][t * 512]);
        gload_lds16(Vg + (size_t)(t * 8 + krr) * Sn + kb + kchunk * 8, &Vs[nxt][t * 512]);
      }
    }

    // compute on buf[cur]: 64 keys as 2 chunks of 32
#pragma unroll
    for (int c = 0; c < 2; ++c) {
      short8 kf[2][2];
#pragma unroll
      for (int t2 = 0; t2 < 2; ++t2)
#pragma unroll
        for (int ks = 0; ks < 2; ++ks)
          kf[t2][ks] = *(const short8*)(
              &Ks[cur][(c * 32 + t2 * 16 + l16) * 64 + (((ks * 4 + quad) ^ l8) << 3)]);

      f32x4 sacc[2][2];
#pragma unroll
      for (int mi = 0; mi < 2; ++mi)
#pragma unroll
        for (int t2 = 0; t2 < 2; ++t2)
          sacc[mi][t2] = mfma_bf16(kf[t2][1], qf[mi][1],
                                   mfma_bf16(kf[t2][0], qf[mi][0], kZero));

      short8 vf[4];
#pragma unroll
      for (int nv = 0; nv < 4; ++nv)
        vf[nv] = *(const short8*)(
            &Vs[cur][(nv * 16 + l16) * 64 + (((c * 4 + quad) ^ l8) << 3)]);

#pragma unroll
      for (int mi = 0; mi < 2; ++mi) {
        f32x4 s0 = sacc[mi][0], s1 = sacc[mi][1];
        float p1a[4], p1b[4], p2a[4], p2b[4];
#pragma unroll
        for (int r = 0; r < 4; ++r) {
          p1a[r] = __builtin_amdgcn_exp2f(s0[r]);
          p1b[r] = __builtin_amdgcn_exp2f(s1[r]);
          float t0 = fmaxf(s0[r], 0.f), t1 = fmaxf(s1[r], 0.f);
          p2a[r] = t0 * t0;
          p2b[r] = t1 * t1;
        }
        short8 pf1 = transpose_to_bfrag(cvt_pk_bf16(p1a[0], p1a[1]),
                                        cvt_pk_bf16(p1a[2], p1a[3]),
                                        cvt_pk_bf16(p1b[0], p1b[1]),
                                        cvt_pk_bf16(p1b[2], p1b[3]));
        short8 pf2 = transpose_to_bfrag(cvt_pk_bf16(p2a[0], p2a[1]),
                                        cvt_pk_bf16(p2a[2], p2a[3]),
                                        cvt_pk_bf16(p2b[0], p2b[1]),
                                        cvt_pk_bf16(p2b[2], p2b[3]));
#pragma unroll
        for (int nv = 0; nv < 4; ++nv) {
          acc_s[mi][nv] = mfma_bf16(vf[nv], pf1, acc_s[mi][nv]);
          acc_r2[mi][nv] = mfma_bf16(vf[nv], pf2, acc_r2[mi][nv]);
        }
        lacc[mi] = mfma_bf16(ones, pf1, lacc[mi]);  // D[*][q] = sum_k p1
      }
    }
    __syncthreads();  // (a) drains prefetch (landed during compute)
                      // (b) protects buf[cur] before kt+1 restages it
  }

  float w0 = wmix[0], w1 = wmix[1];
  float e0 = __expf(w0), e1 = __expf(w1);
  float mix0 = e0 / (e0 + e1);
  float mix1 = (e1 / (e0 + e1)) * kR2Fix;  // undo (log2e)^2 in relu^2 branch

#pragma unroll
  for (int mi = 0; mi < 2; ++mi) {
    float a0 = mix0 / lacc[mi][0];
    int srow = qt * 128 + wave * 32 + mi * 16 + l16;
#pragma unroll
    for (int nv = 0; nv < 4; ++nv) {
      float v0 = fmaf(acc_s[mi][nv][0], a0, mix1 * acc_r2[mi][nv][0]);
      float v1 = fmaf(acc_s[mi][nv][1], a0, mix1 * acc_r2[mi][nv][1]);
      float v2 = fmaf(acc_s[mi][nv][2], a0, mix1 * acc_r2[mi][nv][2]);
      float v3 = fmaf(acc_s[mi][nv][3], a0, mix1 * acc_r2[mi][nv][3]);
      uint2 o;
      o.x = cvt_pk_bf16(v0, v1);
      o.y = cvt_pk_bf16(v2, v3);
      *(uint2*)(&Ctx[(size_t)(b * Sn + srow) * Dm + h * 64 + nv * 16 + quad * 4]) = o;
    }
  }
}

// ---------------- output projection GEMM (fp32 out) ----------------
__global__ __launch_bounds__(256, 3) void k_gemm_out(
    const unsigned short* __restrict__ Abf, const unsigned short* __restrict__ W,
    const float* __restrict__ bias, float* __restrict__ out) {
  __shared__ unsigned short As[128 * 32];
  __shared__ unsigned short Bs[128 * 32];

  const int tid = threadIdx.x;
  const int wave = tid >> 6, lane = tid & 63;
  const int wm = wave >> 1, wn = wave & 1;
  const int quad = lane >> 4, l16 = lane & 15;
  const int bm = blockIdx.y * 128, bn = blockIdx.x * 128;

  const int sr = lane >> 2;
  const int sc = (lane & 3) * 8;
  const unsigned short* gA0 = Abf + (size_t)(bm + (wave * 2 + 0) * 16 + sr) * Dm + sc;
  const unsigned short* gA1 = Abf + (size_t)(bm + (wave * 2 + 1) * 16 + sr) * Dm + sc;
  const unsigned short* gB0 = W + (size_t)(bn + (wave * 2 + 0) * 16 + sr) * Dm + sc;
  const unsigned short* gB1 = W + (size_t)(bn + (wave * 2 + 1) * 16 + sr) * Dm + sc;
  unsigned short* lA0 = &As[(wave * 2 + 0) * 512];
  unsigned short* lA1 = &As[(wave * 2 + 1) * 512];
  unsigned short* lB0 = &Bs[(wave * 2 + 0) * 512];
  unsigned short* lB1 = &Bs[(wave * 2 + 1) * 512];

  f32x4 acc[4][4];
#pragma unroll
  for (int i = 0; i < 4; ++i)
#pragma unroll
    for (int j = 0; j < 4; ++j)
#pragma unroll
      for (int r = 0; r < 4; ++r) acc[i][j][r] = 0.f;

  for (int kk = 0; kk < Dm; kk += 32) {
    gload_lds16(gA0 + kk, lA0);
    gload_lds16(gA1 + kk, lA1);
    gload_lds16(gB0 + kk, lB0);
    gload_lds16(gB1 + kk, lB1);
    __syncthreads();
    short8 af[4], bf[4];
#pragma unroll
    for (int mi = 0; mi < 4; ++mi)
      af[mi] = *(const short8*)(&As[(wm * 64 + mi * 16 + l16) * 32 + quad * 8]);
#pragma unroll
    for (int ni = 0; ni < 4; ++ni)
      bf[ni] = *(const short8*)(&Bs[(wn * 64 + ni * 16 + l16) * 32 + quad * 8]);
#pragma unroll
    for (int mi = 0; mi < 4; ++mi)
#pragma unroll
      for (int ni = 0; ni < 4; ++ni)
        acc[mi][ni] = mfma_bf16(af[mi], bf[ni], acc[mi][ni]);
    __syncthreads();
  }

#pragma unroll
  for (int ni = 0; ni < 4; ++ni) {
    int n = bn + wn * 64 + ni * 16 + l16;
    float bias_v = bias[n];
#pragma unroll
    for (int mi = 0; mi < 4; ++mi) {
#pragma unroll
      for (int r = 0; r < 4; ++r) {
        int m = bm + wm * 64 + mi * 16 + quad * 4 + r;
        out[(size_t)m * Dm + n] = acc[mi][ni][r] + bias_v;
      }
    }
  }
}

extern "C" void kernel_launch(void* const* d_in, const int* in_sizes, int n_in,
                              void* d_out, int out_size, void* d_ws, size_t ws_size,
                              hipStream_t stream) {
  const float* hs = (const float*)d_in[0];
  const float* Wq = (const float*)d_in[1];
  const float* bq = (const float*)d_in[2];
  const float* Wk = (const float*)d_in[3];
  const float* bk = (const float*)d_in[4];
  const float* Wv = (const float*)d_in[5];
  const float* bv = (const float*)d_in[6];
  const float* Wo = (const float*)d_in[7];
  const float* bo = (const float*)d_in[8];
  const float* wmix = (const float*)d_in[9];

  unsigned short* hbf = (unsigned short*)d_ws;          // 8192*768
  unsigned short* wbf = hbf + (size_t)Mn * Dm;          // 4*768*768 ([Wq;Wk;Wv;Wo])
  unsigned short* Qb  = wbf + (size_t)4 * Dm * Dm;      // 8192*768
  unsigned short* Kb  = Qb + (size_t)Mn * Dm;           // 8192*768
  unsigned short* Vt  = Kb + (size_t)Mn * Dm;           // 48*64*2048
  unsigned short* Ctx = hbf;                            // reuse (hbf dead after QKV)

  k_cast_all<<<dim3(8448), dim3(256), 0, stream>>>(hs, Wq, Wk, Wv, Wo, hbf, wbf);
  k_gemm_qkv<<<dim3(12, 64), dim3(256), 0, stream>>>(hbf, wbf, bq, bk, bv, Qb, Kb, Vt);
  k_attn<<<dim3(768), dim3(256), 0, stream>>>(Qb, Kb, Vt, wmix, Ctx);
  k_gemm_out<<<dim3(6, 64), dim3(256), 0, stream>>>(Ctx, wbf + (size_t)3 * Dm * Dm, bo,
                                                    (float*)d_out);
}